// Round 2
// baseline (702.427 us; speedup 1.0000x reference)
//
#include <hip/hip_runtime.h>

// Problem constants
#define D_MODEL 1024
#define RANK    256
#define NBATCH  4
#define TSEQ    2048
#define MROWS   (NBATCH * TSEQ)   // 8192
#define NCAT    1280              // 512 (a_b|a_t) + 512 (kb|kt) + 256 (xt)
#define NE      512               // E width

// ---- workspace layout (float offsets) ----
#define OFF_PCAT  0u                            // [1024][1280]
#define OFF_VC    (OFF_PCAT + 1024u*1280u)      // [1024][512]
#define OFF_WC    (OFF_VC   + 1024u*512u)
#define OFF_UC    (OFF_WC   + 1024u*512u)
#define OFF_G     (OFF_UC   + 1024u*512u)       // Wo@Uc  [1024][512]
#define OFF_B2    (OFF_G    + 1024u*512u)       // [1024]
#define OFF_BIASC (OFF_B2   + 1024u)            // [1024]
#define OFF_Y     (OFF_BIASC+ 1024u)            // [8192][1280]
#define OFF_SCR   (OFF_Y    + (unsigned)MROWS*NCAT)  // [4][32][768]
// total = OFF_SCR + 4*32*768 = 13,993,984 floats ~= 56 MB

// ================= GEMM =================
// C[M][N] = A ? B.  BNN: B is [K][N] row-major (NN); else B is [N][K] (NT).
// AT: A is [K][M] row-major (TN); else A is [M][K].
// EPI==1: C = acc * (1/((m%Tmod)+1)) + bias[n]
#define BM 64
#define BN 64
#define BK 16

template <int BNN, int AT, int EPI>
__global__ __launch_bounds__(256) void gemm_kernel(
    const float* __restrict__ A, const float* __restrict__ Bm,
    float* __restrict__ C, int M, int N, int K, int ldA, int ldB, int ldC,
    const float* __restrict__ bias, int Tmod) {
  __shared__ float As[BK][BM + 4];
  __shared__ float Bs[BK][BN + 4];
  const int tid = threadIdx.x;
  const int tx = tid & 15, ty = tid >> 4;
  const int n0 = blockIdx.x * BN, m0 = blockIdx.y * BM;

  float acc[4][4] = {};

  for (int k0 = 0; k0 < K; k0 += BK) {
    // ---- load A tile ----
    if (AT == 0) {
      const int r = tid >> 2;           // 0..63 (row in tile)
      const int kq = (tid & 3) * 4;     // 0,4,8,12
      const float4 v = *(const float4*)&A[(size_t)(m0 + r) * ldA + k0 + kq];
      As[kq + 0][r] = v.x; As[kq + 1][r] = v.y;
      As[kq + 2][r] = v.z; As[kq + 3][r] = v.w;
    } else {
      const int kk = tid >> 4;          // 0..15
      const int mq = (tid & 15) * 4;    // 0..60
      const float4 v = *(const float4*)&A[(size_t)(k0 + kk) * ldA + m0 + mq];
      *(float4*)&As[kk][mq] = v;
    }
    // ---- load B tile ----
    if (BNN) {
      const int kk = tid >> 4;
      const int nq = (tid & 15) * 4;
      const float4 v = *(const float4*)&Bm[(size_t)(k0 + kk) * ldB + n0 + nq];
      *(float4*)&Bs[kk][nq] = v;
    } else {
      const int r = tid >> 2;           // n in tile
      const int kq = (tid & 3) * 4;
      const float4 v = *(const float4*)&Bm[(size_t)(n0 + r) * ldB + k0 + kq];
      Bs[kq + 0][r] = v.x; Bs[kq + 1][r] = v.y;
      Bs[kq + 2][r] = v.z; Bs[kq + 3][r] = v.w;
    }
    __syncthreads();

#pragma unroll
    for (int kk = 0; kk < BK; ++kk) {
      const float4 av = *(const float4*)&As[kk][ty * 4];
      const float4 bv = *(const float4*)&Bs[kk][tx * 4];
      const float a_[4] = {av.x, av.y, av.z, av.w};
      const float b_[4] = {bv.x, bv.y, bv.z, bv.w};
#pragma unroll
      for (int i = 0; i < 4; ++i)
#pragma unroll
        for (int j = 0; j < 4; ++j)
          acc[i][j] = fmaf(a_[i], b_[j], acc[i][j]);
    }
    __syncthreads();
  }

#pragma unroll
  for (int i = 0; i < 4; ++i) {
    const int m = m0 + ty * 4 + i;
    float inv = 1.0f;
    if (EPI == 1) inv = 1.0f / (float)((m % Tmod) + 1);
    float4 ov;
    float* o = (float*)&ov;
#pragma unroll
    for (int j = 0; j < 4; ++j) {
      float v = acc[i][j];
      if (EPI == 1) v = v * inv + bias[n0 + tx * 4 + j];
      o[j] = v;
    }
    *(float4*)&C[(size_t)m * ldC + n0 + tx * 4] = ov;
  }
}

// ================= prep: concatenated weights =================
__global__ void prep_concat(const float* __restrict__ Vb, const float* __restrict__ Vt,
                            const float* __restrict__ Wb, const float* __restrict__ Wt,
                            const float* __restrict__ Ub, const float* __restrict__ Ut,
                            const float* __restrict__ Xt,
                            const float* __restrict__ bias_b, const float* __restrict__ bias_t,
                            const float* __restrict__ alpha_p,
                            float* __restrict__ Vc, float* __restrict__ Wc,
                            float* __restrict__ Uc, float* __restrict__ Pcat,
                            float* __restrict__ bias_c) {
  const int d = blockIdx.x;    // 0..1023
  const int c = threadIdx.x;   // 0..255
  const float al = *alpha_p;
  Vc[d * 512 + c]       = Vb[d * 256 + c];
  Vc[d * 512 + 256 + c] = Vt[d * 256 + c];
  Wc[d * 512 + c]       = Wb[d * 256 + c];
  Wc[d * 512 + 256 + c] = Wt[d * 256 + c];
  Uc[d * 512 + c]       = Ub[d * 256 + c];
  Uc[d * 512 + 256 + c] = Ut[d * 256 + c];
  Pcat[(size_t)d * NCAT + 1024 + c] = Xt[d * 256 + c];
  if (c == 0) bias_c[d] = bias_b[d] + al * bias_t[d];
}

// b2 = Wo @ bias_c  (block per output row, coalesced row read + reduce)
__global__ void bias_proj(const float* __restrict__ Wo, const float* __restrict__ bias_c,
                          float* __restrict__ b2) {
  const int d = blockIdx.x;
  const int t = threadIdx.x;
  float s = 0.f;
  for (int e = t; e < 1024; e += 256) s += Wo[(size_t)d * 1024 + e] * bias_c[e];
  __shared__ float red[256];
  red[t] = s; __syncthreads();
  for (int off = 128; off > 0; off >>= 1) {
    if (t < off) red[t] += red[t + off];
    __syncthreads();
  }
  if (t == 0) b2[d] = red[0];
}

// ================= hierarchical cumsum along T =================
// cols [512,1280) of Y get inclusive cumsum over t per (b,col);
// cols >= 1024 additionally divided by (t+1). Segments of 64, 32 segs.
#define CUMCOLS 768
__global__ void cumsum_s1(const float* __restrict__ Y, float* __restrict__ scr) {
  const int lane = threadIdx.x;          // 64
  const int cg = blockIdx.x;             // 0..11
  const int seg = blockIdx.y;            // 0..31
  const int b = blockIdx.z;              // 0..3
  const int col = 512 + cg * 64 + lane;
  size_t base = (size_t)(b * TSEQ + seg * 64) * NCAT + col;
  float s = 0.f;
  for (int t = 0; t < 64; ++t) s += Y[base + (size_t)t * NCAT];
  scr[(size_t)(b * 32 + seg) * CUMCOLS + cg * 64 + lane] = s;
}
__global__ void cumsum_s2(float* __restrict__ scr) {
  const int lane = threadIdx.x;
  const int cg = blockIdx.x;
  const int b = blockIdx.z;
  const int c = cg * 64 + lane;
  float run = 0.f;
  for (int seg = 0; seg < 32; ++seg) {
    const size_t idx = (size_t)(b * 32 + seg) * CUMCOLS + c;
    const float v = scr[idx];
    scr[idx] = run;   // exclusive prefix
    run += v;
  }
}
__global__ void cumsum_s3(float* __restrict__ Y, const float* __restrict__ scr) {
  const int lane = threadIdx.x;
  const int cg = blockIdx.x;
  const int seg = blockIdx.y;
  const int b = blockIdx.z;
  const int col = 512 + cg * 64 + lane;
  size_t base = (size_t)(b * TSEQ + seg * 64) * NCAT + col;
  float run = scr[(size_t)(b * 32 + seg) * CUMCOLS + cg * 64 + lane];
  for (int t = 0; t < 64; ++t) {
    const size_t idx = base + (size_t)t * NCAT;
    run += Y[idx];
    float o = run;
    if (col >= 1024) o *= 1.0f / (float)(seg * 64 + t + 1);
    Y[idx] = o;
  }
}

// ================= combine: E in place over Y[:, 0:512] =================
// Y cols: 0..255 a_b | 256..511 a_t | 512..767 c_b | 768..1023 c_t | 1024..1279 z_t
__global__ void combine_E(float* __restrict__ Y, const float* __restrict__ alpha_p) {
  const float al = *alpha_p;
  const int idx = blockIdx.x * blockDim.x + threadIdx.x;
  const int total = MROWS * NE;
  if (idx >= total) return;
  const int t = idx >> 9;          // /512
  const int r = idx & 511;
  const size_t row = (size_t)t * NCAT;
  if (r < 256) {
    Y[row + r] = Y[row + r] * Y[row + 512 + r];
  } else {
    const int r2 = r - 256;
    Y[row + r] = al * Y[row + r] * Y[row + 768 + r2] * Y[row + 1024 + r2];
  }
}

// ================= launch =================
extern "C" void kernel_launch(void* const* d_in, const int* in_sizes, int n_in,
                              void* d_out, int out_size, void* d_ws, size_t ws_size,
                              hipStream_t stream) {
  const float* x      = (const float*)d_in[0];
  const float* Wq     = (const float*)d_in[1];
  const float* Wk     = (const float*)d_in[2];
  const float* Wo     = (const float*)d_in[3];
  const float* Ub     = (const float*)d_in[4];
  const float* Vb     = (const float*)d_in[5];
  const float* Wb     = (const float*)d_in[6];
  const float* bias_b = (const float*)d_in[7];
  const float* Ut     = (const float*)d_in[8];
  const float* Vt     = (const float*)d_in[9];
  const float* Wt     = (const float*)d_in[10];
  const float* Xt     = (const float*)d_in[11];
  const float* bias_t = (const float*)d_in[12];
  const float* alpha  = (const float*)d_in[13];
  float* out = (float*)d_out;
  float* ws  = (float*)d_ws;

  float* Pcat   = ws + OFF_PCAT;
  float* Vc     = ws + OFF_VC;
  float* Wc     = ws + OFF_WC;
  float* Uc     = ws + OFF_UC;
  float* G      = ws + OFF_G;
  float* b2     = ws + OFF_B2;
  float* bias_c = ws + OFF_BIASC;
  float* Y      = ws + OFF_Y;
  float* scr    = ws + OFF_SCR;

  // 1. concat weights, bias_c, copy X_t into Pcat[:,1024:]
  prep_concat<<<1024, 256, 0, stream>>>(Vb, Vt, Wb, Wt, Ub, Ut, Xt, bias_b, bias_t,
                                        alpha, Vc, Wc, Uc, Pcat, bias_c);
  // 2. Pcat[:,0:512)  = Wq^T @ Vc   (TN)
  gemm_kernel<1, 1, 0><<<dim3(512 / BN, 1024 / BM), 256, 0, stream>>>(
      Wq, Vc, Pcat + 0, 1024, 512, 1024, 1024, 512, NCAT, nullptr, 1);
  // 3. Pcat[:,512:1024) = Wk^T @ Wc (TN)
  gemm_kernel<1, 1, 0><<<dim3(512 / BN, 1024 / BM), 256, 0, stream>>>(
      Wk, Wc, Pcat + 512, 1024, 512, 1024, 1024, 512, NCAT, nullptr, 1);
  // 4. G = Wo @ Uc (NN)
  gemm_kernel<1, 0, 0><<<dim3(512 / BN, 1024 / BM), 256, 0, stream>>>(
      Wo, Uc, G, 1024, 512, 1024, 1024, 512, 512, nullptr, 1);
  // 5. b2 = Wo @ bias_c
  bias_proj<<<1024, 256, 0, stream>>>(Wo, bias_c, b2);
  // 6. Y = x @ Pcat  (NN, the big one: 8192 x 1280 x 1024)
  gemm_kernel<1, 0, 0><<<dim3(NCAT / BN, MROWS / BM), 256, 0, stream>>>(
      x, Pcat, Y, MROWS, NCAT, 1024, 1024, NCAT, NCAT, nullptr, 1);
  // 7-9. causal cumsum on Y[:,512:1280), with /count on cols >= 1024
  cumsum_s1<<<dim3(12, 32, NBATCH), 64, 0, stream>>>(Y, scr);
  cumsum_s2<<<dim3(12, 1, NBATCH), 64, 0, stream>>>(scr);
  cumsum_s3<<<dim3(12, 32, NBATCH), 64, 0, stream>>>(Y, scr);
  // 10. E in place over Y[:,0:512)
  combine_E<<<(MROWS * NE + 255) / 256, 256, 0, stream>>>(Y, alpha);
  // 11. out = diag(1/counts) * (E @ G^T) + b2   (NT + epilogue)
  gemm_kernel<0, 0, 1><<<dim3(1024 / BN, MROWS / BM), 256, 0, stream>>>(
      Y, G, out, MROWS, 1024, 512, NCAT, 512, 1024, b2, TSEQ);
}

// Round 3
// 382.627 us; speedup vs baseline: 1.8358x; 1.8358x over previous
//
#include <hip/hip_runtime.h>

// Problem constants
#define D_MODEL 1024
#define RANK    256
#define NBATCH  4
#define TSEQ    2048
#define MROWS   (NBATCH * TSEQ)   // 8192
#define NCAT    1280              // 512 (a_b|a_t) + 512 (c_b|c_t) + 256 (z_t)
#define NE      512

// ---- workspace layout (float offsets; all 1K-float aligned) ----
#define OFF_VC    0u                         // [1024][512] f32
#define OFF_WC    524288u
#define OFF_UC    1048576u
#define OFF_BIASC 1572864u                   // [1024]
#define OFF_B2    1573888u                   // [1024]
#define OFF_PB    1574912u                   // PcatT bf16 [1280][1024] (655360 f)
#define OFF_GB    2230272u                   // G bf16 [1024][512]      (262144 f)
#define OFF_Y     2492416u                   // f32 [8192][1280]        (10485760 f)
#define OFF_SCR   12978176u                  // f32 [4][32][768]        (98304 f)
#define OFF_XB    13076480u                  // x bf16 [8192][1024]     (4194304 f)
#define OFF_EB    OFF_XB                     // E bf16 [8192][512] (aliases xb; xb dead)
// total 17,270,784 floats = 69.1 MB

typedef __attribute__((ext_vector_type(8))) short bf16x8;
typedef __attribute__((ext_vector_type(4))) float f32x4;

__device__ __forceinline__ unsigned short f2bf(float f) {
  union { float f; unsigned u; } v; v.f = f;
  return (unsigned short)((v.u + 0x7fff + ((v.u >> 16) & 1)) >> 16);  // RNE
}

__device__ __forceinline__ void gload16(const void* g, void* l) {
  __builtin_amdgcn_global_load_lds(
      (const __attribute__((address_space(1))) unsigned*)g,
      (__attribute__((address_space(3))) unsigned*)l, 16, 0, 0);
}

// ================= bf16 MFMA GEMM, NT: C[M][N] = A[M][K] * B[N][K]^T ===========
// 128x128 tile, BK=32, 4 waves (2x2), each wave 64x64 (4x4 frags of 16x16x32).
// EPI==1: C = acc / ((m & 2047)+1) + bias[n]
template <int EPI>
__global__ __launch_bounds__(256) void mfma_nt(
    const short* __restrict__ A, const short* __restrict__ B,
    float* __restrict__ C, int K, int ldA, int ldB, int ldC,
    const float* __restrict__ bias) {
  __shared__ short As[128 * 32];
  __shared__ short Bs[128 * 32];
  const int tid = threadIdx.x;
  const int m0 = blockIdx.y * 128, n0 = blockIdx.x * 128;
  const int l = tid & 63;
  const int wv = tid >> 6;
  const int wm = (wv >> 1) * 64, wn = (wv & 1) * 64;

  // staging: thread -> (row sr, k-chunk sc); per-wave LDS dests are lane-linear
  const int sr = tid >> 2;
  const int sc = (tid & 3) * 8;
  const short* gA = A + (size_t)(m0 + sr) * ldA + sc;
  const short* gB = B + (size_t)(n0 + sr) * ldB + sc;
  short* lA = As + sr * 32 + sc;
  short* lB = Bs + sr * 32 + sc;

  // fragment read offsets (constant across K-steps)
  const int arow = wm + (l & 15);
  const int brow = wn + (l & 15);
  const int kc = (l >> 4) * 8;

  f32x4 acc[4][4] = {};

  for (int k0 = 0; k0 < K; k0 += 32) {
    gload16(gA, lA);
    gload16(gA + (size_t)64 * ldA, lA + 64 * 32);
    gload16(gB, lB);
    gload16(gB + (size_t)64 * ldB, lB + 64 * 32);
    gA += 32; gB += 32;
    __syncthreads();

    bf16x8 af[4], bfr[4];
#pragma unroll
    for (int m = 0; m < 4; ++m) af[m] = *(const bf16x8*)&As[(arow + m * 16) * 32 + kc];
#pragma unroll
    for (int n = 0; n < 4; ++n) bfr[n] = *(const bf16x8*)&Bs[(brow + n * 16) * 32 + kc];

#pragma unroll
    for (int m = 0; m < 4; ++m)
#pragma unroll
      for (int n = 0; n < 4; ++n)
        acc[m][n] = __builtin_amdgcn_mfma_f32_16x16x32_bf16(af[m], bfr[n], acc[m][n], 0, 0, 0);
    __syncthreads();
  }

  // C/D layout: col = l&15, row = (l>>4)*4 + j   [m89/m91-verified]
  const int cc = wn + (l & 15);
  const int crb = wm + (l >> 4) * 4;
#pragma unroll
  for (int m = 0; m < 4; ++m) {
#pragma unroll
    for (int j = 0; j < 4; ++j) {
      const int gm = m0 + crb + m * 16 + j;
      float inv = 1.0f;
      if (EPI) inv = 1.0f / (float)((gm & (TSEQ - 1)) + 1);
#pragma unroll
      for (int n = 0; n < 4; ++n) {
        const int gn = n0 + cc + n * 16;
        float v = acc[m][n][j];
        if (EPI) v = v * inv + bias[gn];
        C[(size_t)gm * ldC + gn] = v;
      }
    }
  }
}

// ================= fp32 GEMM (prep-sized), optional bf16 output ================
// BNN: B is [K][N] row-major; else [N][K]. AT: A is [K][M]; else [M][K].
#define BM 64
#define BN 64
#define BK 16
template <int BNN, int AT, int OBF>
__global__ __launch_bounds__(256) void gemm_kernel(
    const float* __restrict__ A, const float* __restrict__ Bm,
    float* __restrict__ C, int M, int N, int K, int ldA, int ldB, int ldC) {
  __shared__ float As[BK][BM + 4];
  __shared__ float Bs[BK][BN + 4];
  const int tid = threadIdx.x;
  const int tx = tid & 15, ty = tid >> 4;
  const int n0 = blockIdx.x * BN, m0 = blockIdx.y * BM;
  float acc[4][4] = {};

  for (int k0 = 0; k0 < K; k0 += BK) {
    if (AT == 0) {
      const int r = tid >> 2, kq = (tid & 3) * 4;
      const float4 v = *(const float4*)&A[(size_t)(m0 + r) * ldA + k0 + kq];
      As[kq + 0][r] = v.x; As[kq + 1][r] = v.y; As[kq + 2][r] = v.z; As[kq + 3][r] = v.w;
    } else {
      const int kk = tid >> 4, mq = (tid & 15) * 4;
      *(float4*)&As[kk][mq] = *(const float4*)&A[(size_t)(k0 + kk) * ldA + m0 + mq];
    }
    if (BNN) {
      const int kk = tid >> 4, nq = (tid & 15) * 4;
      *(float4*)&Bs[kk][nq] = *(const float4*)&Bm[(size_t)(k0 + kk) * ldB + n0 + nq];
    } else {
      const int r = tid >> 2, kq = (tid & 3) * 4;
      const float4 v = *(const float4*)&Bm[(size_t)(n0 + r) * ldB + k0 + kq];
      Bs[kq + 0][r] = v.x; Bs[kq + 1][r] = v.y; Bs[kq + 2][r] = v.z; Bs[kq + 3][r] = v.w;
    }
    __syncthreads();
#pragma unroll
    for (int kk = 0; kk < BK; ++kk) {
      const float4 av = *(const float4*)&As[kk][ty * 4];
      const float4 bv = *(const float4*)&Bs[kk][tx * 4];
      const float a_[4] = {av.x, av.y, av.z, av.w};
      const float b_[4] = {bv.x, bv.y, bv.z, bv.w};
#pragma unroll
      for (int i = 0; i < 4; ++i)
#pragma unroll
        for (int j = 0; j < 4; ++j) acc[i][j] = fmaf(a_[i], b_[j], acc[i][j]);
    }
    __syncthreads();
  }
#pragma unroll
  for (int i = 0; i < 4; ++i) {
    const int m = m0 + ty * 4 + i;
    if (OBF) {
      ushort4 ob;
      ob.x = f2bf(acc[i][0]); ob.y = f2bf(acc[i][1]);
      ob.z = f2bf(acc[i][2]); ob.w = f2bf(acc[i][3]);
      *(ushort4*)&((unsigned short*)C)[(size_t)m * ldC + n0 + tx * 4] = ob;
    } else {
      float4 ov; ov.x = acc[i][0]; ov.y = acc[i][1]; ov.z = acc[i][2]; ov.w = acc[i][3];
      *(float4*)&C[(size_t)m * ldC + n0 + tx * 4] = ov;
    }
  }
}

// ================= prep =================
__global__ void prep_concat(const float* __restrict__ Vb, const float* __restrict__ Vt,
                            const float* __restrict__ Wb, const float* __restrict__ Wt,
                            const float* __restrict__ Ub, const float* __restrict__ Ut,
                            const float* __restrict__ Xt,
                            const float* __restrict__ bias_b, const float* __restrict__ bias_t,
                            const float* __restrict__ alpha_p,
                            float* __restrict__ Vc, float* __restrict__ Wc,
                            float* __restrict__ Uc, short* __restrict__ Pb,
                            float* __restrict__ bias_c) {
  const int d = blockIdx.x;    // 0..1023
  const int c = threadIdx.x;   // 0..255
  const float al = *alpha_p;
  Vc[d * 512 + c]       = Vb[d * 256 + c];
  Vc[d * 512 + 256 + c] = Vt[d * 256 + c];
  Wc[d * 512 + c]       = Wb[d * 256 + c];
  Wc[d * 512 + 256 + c] = Wt[d * 256 + c];
  Uc[d * 512 + c]       = Ub[d * 256 + c];
  Uc[d * 512 + 256 + c] = Ut[d * 256 + c];
  // PcatT rows 1024..1279 = X_t^T (bf16)
  Pb[(size_t)(1024 + c) * 1024 + d] = (short)f2bf(Xt[d * 256 + c]);
  if (c == 0) bias_c[d] = bias_b[d] + al * bias_t[d];
}

__global__ void bias_proj(const float* __restrict__ Wo, const float* __restrict__ bias_c,
                          float* __restrict__ b2) {
  const int d = blockIdx.x;
  const int t = threadIdx.x;
  float s = 0.f;
  for (int e = t; e < 1024; e += 256) s += Wo[(size_t)d * 1024 + e] * bias_c[e];
  __shared__ float red[256];
  red[t] = s; __syncthreads();
  for (int off = 128; off > 0; off >>= 1) {
    if (t < off) red[t] += red[t + off];
    __syncthreads();
  }
  if (t == 0) b2[d] = red[0];
}

// ================= f32 -> bf16 convert (vectorized) =================
__global__ void f2b_kernel(const float* __restrict__ in, short* __restrict__ out, int n) {
  const int i = (blockIdx.x * blockDim.x + threadIdx.x) * 4;
  if (i >= n) return;
  const float4 v = *(const float4*)&in[i];
  ushort4 o;
  o.x = f2bf(v.x); o.y = f2bf(v.y); o.z = f2bf(v.z); o.w = f2bf(v.w);
  *(ushort4*)&out[i] = o;
}

// ================= hierarchical cumsum along T (cols 512..1279 of Y) ==========
#define CUMCOLS 768
__global__ void cumsum_s1(const float* __restrict__ Y, float* __restrict__ scr) {
  const int lane = threadIdx.x;
  const int cg = blockIdx.x, seg = blockIdx.y, b = blockIdx.z;
  const int col = 512 + cg * 64 + lane;
  size_t base = (size_t)(b * TSEQ + seg * 64) * NCAT + col;
  float s = 0.f;
  for (int t = 0; t < 64; ++t) s += Y[base + (size_t)t * NCAT];
  scr[(size_t)(b * 32 + seg) * CUMCOLS + cg * 64 + lane] = s;
}
__global__ void cumsum_s2(float* __restrict__ scr) {
  const int lane = threadIdx.x;
  const int cg = blockIdx.x, b = blockIdx.z;
  const int c = cg * 64 + lane;
  float run = 0.f;
  for (int seg = 0; seg < 32; ++seg) {
    const size_t idx = (size_t)(b * 32 + seg) * CUMCOLS + c;
    const float v = scr[idx];
    scr[idx] = run;
    run += v;
  }
}
__global__ void cumsum_s3(float* __restrict__ Y, const float* __restrict__ scr) {
  const int lane = threadIdx.x;
  const int cg = blockIdx.x, seg = blockIdx.y, b = blockIdx.z;
  const int col = 512 + cg * 64 + lane;
  size_t base = (size_t)(b * TSEQ + seg * 64) * NCAT + col;
  float run = scr[(size_t)(b * 32 + seg) * CUMCOLS + cg * 64 + lane];
  for (int t = 0; t < 64; ++t) {
    const size_t idx = base + (size_t)t * NCAT;
    run += Y[idx];
    float o = run;
    if (col >= 1024) o *= 1.0f / (float)(seg * 64 + t + 1);
    Y[idx] = o;
  }
}

// ================= combine -> Eb (bf16 [8192][512]) =================
__global__ void combine_E(const float* __restrict__ Y, short* __restrict__ Eb,
                          const float* __restrict__ alpha_p) {
  const float al = *alpha_p;
  const int idx = blockIdx.x * blockDim.x + threadIdx.x;
  const int row = idx >> 9, r = idx & 511;
  const size_t rb = (size_t)row * NCAT;
  float v;
  if (r < 256) {
    v = Y[rb + r] * Y[rb + 512 + r];
  } else {
    const int r2 = r - 256;
    v = al * Y[rb + r] * Y[rb + 768 + r2] * Y[rb + 1024 + r2];
  }
  Eb[(size_t)row * 512 + r] = (short)f2bf(v);
}

// ================= launch =================
extern "C" void kernel_launch(void* const* d_in, const int* in_sizes, int n_in,
                              void* d_out, int out_size, void* d_ws, size_t ws_size,
                              hipStream_t stream) {
  const float* x      = (const float*)d_in[0];
  const float* Wq     = (const float*)d_in[1];
  const float* Wk     = (const float*)d_in[2];
  const float* Wo     = (const float*)d_in[3];
  const float* Ub     = (const float*)d_in[4];
  const float* Vb     = (const float*)d_in[5];
  const float* Wb     = (const float*)d_in[6];
  const float* bias_b = (const float*)d_in[7];
  const float* Ut     = (const float*)d_in[8];
  const float* Vt     = (const float*)d_in[9];
  const float* Wt     = (const float*)d_in[10];
  const float* Xt     = (const float*)d_in[11];
  const float* bias_t = (const float*)d_in[12];
  const float* alpha  = (const float*)d_in[13];
  float* out = (float*)d_out;
  float* ws  = (float*)d_ws;

  float* Vc     = ws + OFF_VC;
  float* Wc     = ws + OFF_WC;
  float* Uc     = ws + OFF_UC;
  float* bias_c = ws + OFF_BIASC;
  float* b2     = ws + OFF_B2;
  short* Pb     = (short*)(ws + OFF_PB);   // PcatT bf16 [1280][1024]
  short* Gb     = (short*)(ws + OFF_GB);   // G bf16 [1024][512]
  float* Y      = ws + OFF_Y;
  float* scr    = ws + OFF_SCR;
  short* xb     = (short*)(ws + OFF_XB);
  short* Eb     = (short*)(ws + OFF_EB);   // aliases xb (dead after GEMM1)

  // 1. concat weights (fp32), X_t^T -> Pb rows 1024.., bias_c
  prep_concat<<<1024, 256, 0, stream>>>(Vb, Vt, Wb, Wt, Ub, Ut, Xt, bias_b, bias_t,
                                        alpha, Vc, Wc, Uc, Pb, bias_c);
  // 2. Pb rows 0..511   = (Vc^T @ Wq) bf16   [M=512,N=1024,K=1024]
  gemm_kernel<1, 1, 1><<<dim3(1024 / BN, 512 / BM), 256, 0, stream>>>(
      Vc, Wq, (float*)Pb, 512, 1024, 1024, 512, 1024, 1024);
  // 3. Pb rows 512..1023 = (Wc^T @ Wk) bf16
  gemm_kernel<1, 1, 1><<<dim3(1024 / BN, 512 / BM), 256, 0, stream>>>(
      Wc, Wk, (float*)(Pb + (size_t)512 * 1024), 512, 1024, 1024, 512, 1024, 1024);
  // 4. Gb = (Wo @ Uc) bf16   [M=1024,N=512,K=1024]
  gemm_kernel<1, 0, 1><<<dim3(512 / BN, 1024 / BM), 256, 0, stream>>>(
      Wo, Uc, (float*)Gb, 1024, 512, 1024, 1024, 512, 512);
  // 5. b2 = Wo @ bias_c
  bias_proj<<<1024, 256, 0, stream>>>(Wo, bias_c, b2);
  // 6. xb = bf16(x)
  f2b_kernel<<<(MROWS * 1024 / 4 + 255) / 256, 256, 0, stream>>>(x, xb, MROWS * 1024);
  // 7. Y = xb @ Pb^T  (MFMA, M=8192,N=1280,K=1024)
  mfma_nt<0><<<dim3(NCAT / 128, MROWS / 128), 256, 0, stream>>>(
      xb, Pb, Y, 1024, 1024, 1024, NCAT, nullptr);
  // 8-10. causal cumsum on Y[:,512:1280), /count on cols >= 1024
  cumsum_s1<<<dim3(12, 32, NBATCH), 64, 0, stream>>>(Y, scr);
  cumsum_s2<<<dim3(12, 1, NBATCH), 64, 0, stream>>>(scr);
  cumsum_s3<<<dim3(12, 32, NBATCH), 64, 0, stream>>>(Y, scr);
  // 11. Eb = bf16(E)
  combine_E<<<(MROWS * NE + 255) / 256, 256, 0, stream>>>(Y, Eb, alpha);
  // 12. out = diag(1/counts) * (Eb @ Gb^T) + b2  (MFMA, M=8192,N=1024,K=512)
  mfma_nt<1><<<dim3(1024 / 128, MROWS / 128), 256, 0, stream>>>(
      Eb, Gb, out, 512, 512, 512, 1024, b2);
}

// Round 4
// 240.158 us; speedup vs baseline: 2.9249x; 1.5932x over previous
//
#include <hip/hip_runtime.h>

// Problem constants
#define D_MODEL 1024
#define RANK    256
#define NBATCH  4
#define TSEQ    2048
#define MROWS   (NBATCH * TSEQ)   // 8192
#define NCAT    1280              // 512 (a_b|a_t) + 512 (c_b|c_t) + 256 (z_t)
#define NE      512

// ---- workspace layout (float offsets) ----
#define OFF_WQT   0u                          // Wq^T bf16 [1024][1024] (524288 f)
#define OFF_WKT   524288u                     // Wk^T bf16 [1024][1024]
#define OFF_WOB   1048576u                    // Wo   bf16 [1024][1024]
#define OFF_VCT   1572864u                    // Vc^T bf16 [512][1024]  (262144 f)
#define OFF_WCT   1835008u                    // Wc^T bf16 [512][1024]
#define OFF_UCT   2097152u                    // Uc^T bf16 [512][1024]
#define OFF_B2    2359296u                    // [1024] f32
#define OFF_PB    2360320u                    // PcatT bf16 [1280][1024] (655360 f)
#define OFF_GB    3015680u                    // G bf16 [1024][512]      (262144 f)
#define OFF_Y     3277824u                    // f32 [8192][1280]        (10485760 f)
#define OFF_SCR   13763584u                   // f32 [4][32][768]        (98304 f)
#define OFF_XB    13861888u                   // x bf16 [8192][1024]     (4194304 f)
#define OFF_EB    OFF_XB                      // E bf16 [8192][512] (aliases xb)
// total 18,056,192 floats = 72.2 MB

typedef __attribute__((ext_vector_type(8))) short bf16x8;
typedef __attribute__((ext_vector_type(4))) float f32x4;

__device__ __forceinline__ unsigned short f2bf(float f) {
  union { float f; unsigned u; } v; v.f = f;
  return (unsigned short)((v.u + 0x7fff + ((v.u >> 16) & 1)) >> 16);  // RNE
}

__device__ __forceinline__ void gload16(const void* g, void* l) {
  __builtin_amdgcn_global_load_lds(
      (const __attribute__((address_space(1))) unsigned*)g,
      (__attribute__((address_space(3))) unsigned*)l, 16, 0, 0);
}

// ============ bf16 MFMA NT tile: C[m0:m0+128][n0:n0+128] = A[M][K]*B[N][K]^T ===
// 4 waves (2x2), each wave 64x64 (4x4 frags of 16x16x32). BK=32.
// EPI==1: C = acc / ((m & 2047)+1) + bias[n].  OBF==1: C is bf16.
template <int EPI, int OBF>
__device__ __forceinline__ void mfma_tile(
    const short* __restrict__ A, const short* __restrict__ B, void* __restrict__ Cv,
    int K, int ldA, int ldB, int ldC, int m0, int n0,
    const float* __restrict__ bias, short* As, short* Bs) {
  const int tid = threadIdx.x;
  const int l = tid & 63;
  const int wv = tid >> 6;
  const int wm = (wv >> 1) * 64, wn = (wv & 1) * 64;

  // staging: per-wave LDS dests are lane-linear (16B stride)
  const int sr = tid >> 2;
  const int sc = (tid & 3) * 8;
  const short* gA = A + (size_t)(m0 + sr) * ldA + sc;
  const short* gB = B + (size_t)(n0 + sr) * ldB + sc;
  short* lA = As + sr * 32 + sc;
  short* lB = Bs + sr * 32 + sc;

  const int arow = wm + (l & 15);
  const int brow = wn + (l & 15);
  const int kc = (l >> 4) * 8;

  f32x4 acc[4][4] = {};

  for (int k0 = 0; k0 < K; k0 += 32) {
    gload16(gA, lA);
    gload16(gA + (size_t)64 * ldA, lA + 64 * 32);
    gload16(gB, lB);
    gload16(gB + (size_t)64 * ldB, lB + 64 * 32);
    gA += 32; gB += 32;
    __syncthreads();

    bf16x8 af[4], bfr[4];
#pragma unroll
    for (int m = 0; m < 4; ++m) af[m] = *(const bf16x8*)&As[(arow + m * 16) * 32 + kc];
#pragma unroll
    for (int n = 0; n < 4; ++n) bfr[n] = *(const bf16x8*)&Bs[(brow + n * 16) * 32 + kc];

#pragma unroll
    for (int m = 0; m < 4; ++m)
#pragma unroll
      for (int n = 0; n < 4; ++n)
        acc[m][n] = __builtin_amdgcn_mfma_f32_16x16x32_bf16(af[m], bfr[n], acc[m][n], 0, 0, 0);
    __syncthreads();
  }

  // C/D layout: col = l&15, row = (l>>4)*4 + j
  const int cc = wn + (l & 15);
  const int crb = wm + (l >> 4) * 4;
#pragma unroll
  for (int m = 0; m < 4; ++m) {
#pragma unroll
    for (int j = 0; j < 4; ++j) {
      const int gm = m0 + crb + m * 16 + j;
      float inv = 1.0f;
      if (EPI) inv = 1.0f / (float)((gm & (TSEQ - 1)) + 1);
#pragma unroll
      for (int n = 0; n < 4; ++n) {
        const int gn = n0 + cc + n * 16;
        float v = acc[m][n][j];
        if (EPI) v = v * inv + bias[gn];
        if (OBF) ((short*)Cv)[(size_t)gm * ldC + gn] = (short)f2bf(v);
        else     ((float*)Cv)[(size_t)gm * ldC + gn] = v;
      }
    }
  }
}

template <int EPI>
__global__ __launch_bounds__(256) void mfma_nt(
    const short* __restrict__ A, const short* __restrict__ B,
    float* __restrict__ C, int K, int ldA, int ldB, int ldC,
    const float* __restrict__ bias) {
  __shared__ short As[128 * 32];
  __shared__ short Bs[128 * 32];
  mfma_tile<EPI, 0>(A, B, C, K, ldA, ldB, ldC,
                    blockIdx.y * 128, blockIdx.x * 128, bias, As, Bs);
}

// batched prep: 96 blocks = 3 GEMMs x 32 tiles (all K=1024, bf16 out)
// g0: Pb[0:512]    = VCT @ WQT^T   [512 x 1024]
// g1: Pb[512:1024] = WCT @ WKT^T   [512 x 1024]
// g2: Gb           = WOB @ UCT^T   [1024 x 512]
__global__ __launch_bounds__(256) void prep_mfma(
    const short* __restrict__ VCT, const short* __restrict__ WQT,
    const short* __restrict__ WCT, const short* __restrict__ WKT,
    const short* __restrict__ WOB, const short* __restrict__ UCT,
    short* __restrict__ Pb, short* __restrict__ Gb) {
  __shared__ short As[128 * 32];
  __shared__ short Bs[128 * 32];
  const int g = blockIdx.x >> 5, t = blockIdx.x & 31;
  if (g == 0)
    mfma_tile<0, 1>(VCT, WQT, Pb, 1024, 1024, 1024, 1024,
                    (t >> 3) * 128, (t & 7) * 128, nullptr, As, Bs);
  else if (g == 1)
    mfma_tile<0, 1>(WCT, WKT, Pb + (size_t)512 * 1024, 1024, 1024, 1024, 1024,
                    (t >> 3) * 128, (t & 7) * 128, nullptr, As, Bs);
  else
    mfma_tile<0, 1>(WOB, UCT, Gb, 1024, 1024, 1024, 512,
                    (t >> 2) * 128, (t & 3) * 128, nullptr, As, Bs);
}

// ============ transpose+convert: O[r][d] = bf16(src[d][c0+rlocal]) =============
// 960 blocks: 0..383 panels (VCT/WCT/UCT from [1024][256] pairs), 384..447 Xt^T
// into Pb rows 1024.., 448..959 WQT/WKT from [1024][1024].
__global__ __launch_bounds__(256) void trans_kernel(
    const float* __restrict__ Vb, const float* __restrict__ Vt,
    const float* __restrict__ Wb, const float* __restrict__ Wt,
    const float* __restrict__ Ub, const float* __restrict__ Ut,
    const float* __restrict__ Xt, const float* __restrict__ Wq,
    const float* __restrict__ Wk,
    short* __restrict__ VCT, short* __restrict__ WCT, short* __restrict__ UCT,
    short* __restrict__ PbXt, short* __restrict__ WQT, short* __restrict__ WKT) {
  const int bid = blockIdx.x;
  const int tid = threadIdx.x;
  const float* src; short* O; int r0, d0, c0, ldS;
  if (bid < 384) {
    const int z = bid >> 7, t = bid & 127;
    r0 = (t >> 4) * 64; d0 = (t & 15) * 64; ldS = 256;
    const float* S0 = z == 0 ? Vb : z == 1 ? Wb : Ub;
    const float* S1 = z == 0 ? Vt : z == 1 ? Wt : Ut;
    O = z == 0 ? VCT : z == 1 ? WCT : UCT;
    src = (r0 < 256) ? S0 : S1; c0 = r0 & 255;
  } else if (bid < 448) {
    const int t = bid - 384;  // 0..63 -> [256][1024]
    r0 = (t >> 4) * 64; d0 = (t & 15) * 64; ldS = 256;
    src = Xt; c0 = r0; O = PbXt;
  } else {
    const int t = bid - 448;  // 0..511
    const int w = t >> 8, tt = t & 255;
    r0 = (tt >> 4) * 64; d0 = (tt & 15) * 64; ldS = 1024;
    src = w ? Wk : Wq; O = w ? WKT : WQT; c0 = r0;
  }
  __shared__ float Ts[64][65];
  const int lr = tid >> 4;         // 0..15
  const int lc = (tid & 15) * 4;   // 0..60
#pragma unroll
  for (int p = 0; p < 4; ++p) {
    const int row = lr + p * 16;
    const float4 v = *(const float4*)&src[(size_t)(d0 + row) * ldS + c0 + lc];
    Ts[row][lc + 0] = v.x; Ts[row][lc + 1] = v.y;
    Ts[row][lc + 2] = v.z; Ts[row][lc + 3] = v.w;
  }
  __syncthreads();
#pragma unroll
  for (int p = 0; p < 4; ++p) {
    const int ri = lr + p * 16;
    ushort4 o;
    o.x = f2bf(Ts[lc + 0][ri]); o.y = f2bf(Ts[lc + 1][ri]);
    o.z = f2bf(Ts[lc + 2][ri]); o.w = f2bf(Ts[lc + 3][ri]);
    *(ushort4*)&((unsigned short*)O)[(size_t)(r0 + ri) * 1024 + d0 + lc] = o;
  }
}

// ================= f32 -> bf16 convert (vectorized) =================
__global__ void f2b_kernel(const float* __restrict__ in, short* __restrict__ out, int n) {
  const int i = (blockIdx.x * blockDim.x + threadIdx.x) * 4;
  if (i >= n) return;
  const float4 v = *(const float4*)&in[i];
  ushort4 o;
  o.x = f2bf(v.x); o.y = f2bf(v.y); o.z = f2bf(v.z); o.w = f2bf(v.w);
  *(ushort4*)&out[i] = o;
}

// b2 = Wo @ (bias_b + alpha*bias_t)
__global__ void bias_proj(const float* __restrict__ Wo, const float* __restrict__ bias_b,
                          const float* __restrict__ bias_t, const float* __restrict__ alpha_p,
                          float* __restrict__ b2) {
  const float al = *alpha_p;
  const int d = blockIdx.x;
  const int t = threadIdx.x;
  float s = 0.f;
  for (int e = t; e < 1024; e += 256)
    s += Wo[(size_t)d * 1024 + e] * (bias_b[e] + al * bias_t[e]);
  __shared__ float red[256];
  red[t] = s; __syncthreads();
  for (int off = 128; off > 0; off >>= 1) {
    if (t < off) red[t] += red[t + off];
    __syncthreads();
  }
  if (t == 0) b2[d] = red[0];
}

// ============ hierarchical cumsum along T (cols 512..1279 of Y) ================
#define CUMCOLS 768
__global__ void cumsum_s1(const float* __restrict__ Y, float* __restrict__ scr) {
  const int lane = threadIdx.x;
  const int cg = blockIdx.x, seg = blockIdx.y, b = blockIdx.z;
  const int col = 512 + cg * 64 + lane;
  size_t base = (size_t)(b * TSEQ + seg * 64) * NCAT + col;
  float s = 0.f;
  for (int t = 0; t < 64; ++t) s += Y[base + (size_t)t * NCAT];
  scr[(size_t)(b * 32 + seg) * CUMCOLS + cg * 64 + lane] = s;
}
__global__ void cumsum_s2(float* __restrict__ scr) {
  const int lane = threadIdx.x;
  const int cg = blockIdx.x, b = blockIdx.z;
  const int c = cg * 64 + lane;
  float run = 0.f;
  for (int seg = 0; seg < 32; ++seg) {
    const size_t idx = (size_t)(b * 32 + seg) * CUMCOLS + c;
    const float v = scr[idx];
    scr[idx] = run;
    run += v;
  }
}
__global__ void cumsum_s3(float* __restrict__ Y, const float* __restrict__ scr) {
  const int lane = threadIdx.x;
  const int cg = blockIdx.x, seg = blockIdx.y, b = blockIdx.z;
  const int col = 512 + cg * 64 + lane;
  size_t base = (size_t)(b * TSEQ + seg * 64) * NCAT + col;
  float run = scr[(size_t)(b * 32 + seg) * CUMCOLS + cg * 64 + lane];
  for (int t = 0; t < 64; ++t) {
    const size_t idx = base + (size_t)t * NCAT;
    run += Y[idx];
    float o = run;
    if (col >= 1024) o *= 1.0f / (float)(seg * 64 + t + 1);
    Y[idx] = o;
  }
}

// ================= combine -> Eb (bf16 [8192][512]) =================
__global__ void combine_E(const float* __restrict__ Y, short* __restrict__ Eb,
                          const float* __restrict__ alpha_p) {
  const float al = *alpha_p;
  const int idx = blockIdx.x * blockDim.x + threadIdx.x;
  const int row = idx >> 9, r = idx & 511;
  const size_t rb = (size_t)row * NCAT;
  float v;
  if (r < 256) {
    v = Y[rb + r] * Y[rb + 512 + r];
  } else {
    const int r2 = r - 256;
    v = al * Y[rb + r] * Y[rb + 768 + r2] * Y[rb + 1024 + r2];
  }
  Eb[(size_t)row * 512 + r] = (short)f2bf(v);
}

// ================= launch =================
extern "C" void kernel_launch(void* const* d_in, const int* in_sizes, int n_in,
                              void* d_out, int out_size, void* d_ws, size_t ws_size,
                              hipStream_t stream) {
  const float* x      = (const float*)d_in[0];
  const float* Wq     = (const float*)d_in[1];
  const float* Wk     = (const float*)d_in[2];
  const float* Wo     = (const float*)d_in[3];
  const float* Ub     = (const float*)d_in[4];
  const float* Vb     = (const float*)d_in[5];
  const float* Wb     = (const float*)d_in[6];
  const float* bias_b = (const float*)d_in[7];
  const float* Ut     = (const float*)d_in[8];
  const float* Vt     = (const float*)d_in[9];
  const float* Wt     = (const float*)d_in[10];
  const float* Xt     = (const float*)d_in[11];
  const float* bias_t = (const float*)d_in[12];
  const float* alpha  = (const float*)d_in[13];
  float* out = (float*)d_out;
  float* ws  = (float*)d_ws;

  short* WQT = (short*)(ws + OFF_WQT);
  short* WKT = (short*)(ws + OFF_WKT);
  short* WOB = (short*)(ws + OFF_WOB);
  short* VCT = (short*)(ws + OFF_VCT);
  short* WCT = (short*)(ws + OFF_WCT);
  short* UCT = (short*)(ws + OFF_UCT);
  float* b2  = ws + OFF_B2;
  short* Pb  = (short*)(ws + OFF_PB);
  short* Gb  = (short*)(ws + OFF_GB);
  float* Y   = ws + OFF_Y;
  float* scr = ws + OFF_SCR;
  short* xb  = (short*)(ws + OFF_XB);
  short* Eb  = (short*)(ws + OFF_EB);

  // 1. transpose+convert weights (panels, Xt^T into Pb rows 1024.., Wq^T, Wk^T)
  trans_kernel<<<960, 256, 0, stream>>>(Vb, Vt, Wb, Wt, Ub, Ut, Xt, Wq, Wk,
                                        VCT, WCT, UCT, Pb + (size_t)1024 * 1024,
                                        WQT, WKT);
  // 2. Wo -> bf16 (row-major, no transpose needed)
  f2b_kernel<<<1024, 256, 0, stream>>>(Wo, WOB, 1024 * 1024);
  // 3. batched prep GEMMs (Pb rows 0..1023, Gb)
  prep_mfma<<<96, 256, 0, stream>>>(VCT, WQT, WCT, WKT, WOB, UCT, Pb, Gb);
  // 4. b2 = Wo @ (bias_b + alpha*bias_t)
  bias_proj<<<1024, 256, 0, stream>>>(Wo, bias_b, bias_t, alpha, b2);
  // 5. xb = bf16(x)
  f2b_kernel<<<8192, 256, 0, stream>>>(x, xb, MROWS * 1024);
  // 6. Y = xb @ Pb^T  (MFMA, M=8192, N=1280, K=1024)
  mfma_nt<0><<<dim3(NCAT / 128, MROWS / 128), 256, 0, stream>>>(
      xb, Pb, Y, 1024, 1024, 1024, NCAT, nullptr);
  // 7-9. causal cumsum on Y[:,512:1280), /count on cols >= 1024
  cumsum_s1<<<dim3(12, 32, NBATCH), 64, 0, stream>>>(Y, scr);
  cumsum_s2<<<dim3(12, 1, NBATCH), 64, 0, stream>>>(scr);
  cumsum_s3<<<dim3(12, 32, NBATCH), 64, 0, stream>>>(Y, scr);
  // 10. Eb = bf16(E)
  combine_E<<<(MROWS * NE + 255) / 256, 256, 0, stream>>>(Y, Eb, alpha);
  // 11. out = diag(1/counts) * (Eb @ Gb^T) + b2  (MFMA, M=8192, N=1024, K=512)
  mfma_nt<1><<<dim3(1024 / 128, MROWS / 128), 256, 0, stream>>>(
      Eb, Gb, out, 512, 512, 512, 1024, b2);
}

// Round 5
// 228.043 us; speedup vs baseline: 3.0802x; 1.0531x over previous
//
#include <hip/hip_runtime.h>

// Problem constants
#define NBATCH  4
#define TSEQ    2048
#define MROWS   8192
#define NCAT    1280              // 512 (a_b|a_t) + 512 (c_b|c_t) + 256 (z_t)
#define NE      512

// ---- workspace layout (float offsets) ----
#define OFF_WQT   0u                          // Wq^T bf16 [1024][1024]
#define OFF_WKT   524288u                     // Wk^T bf16 [1024][1024]
#define OFF_WOB   1048576u                    // Wo   bf16 [1024][1024]
#define OFF_VCT   1572864u                    // Vc^T bf16 [512][1024]
#define OFF_WCT   1835008u                    // Wc^T bf16 [512][1024]
#define OFF_UCT   2097152u                    // Uc^T bf16 [512][1024]
#define OFF_B2    2359296u                    // [1024] f32
#define OFF_PB    2360320u                    // PcatT bf16 [1280][1024]
#define OFF_GB    3015680u                    // G bf16 [1024][512]
#define OFF_Y     3277824u                    // f32 [8192][1280]
#define OFF_SCR   13763584u                   // f32 [4][32][768]
#define OFF_XB    13861888u                   // x bf16 [8192][1024]
#define OFF_EB    OFF_XB                      // E bf16 [8192][512] (aliases xb)

typedef __attribute__((ext_vector_type(8))) short bf16x8;
typedef __attribute__((ext_vector_type(4))) float f32x4;

__device__ __forceinline__ unsigned short f2bf(float f) {
  union { float f; unsigned u; } v; v.f = f;
  return (unsigned short)((v.u + 0x7fff + ((v.u >> 16) & 1)) >> 16);  // RNE
}

__device__ __forceinline__ void gload16(const void* g, void* l) {
  __builtin_amdgcn_global_load_lds(
      (const __attribute__((address_space(1))) unsigned*)g,
      (__attribute__((address_space(3))) unsigned*)l, 16, 0, 0);
}

// ============ bf16 MFMA NT tile, LDS double-buffered 2-phase pipeline =========
// C[m0:+128][n0:+128] = A[M][K]*B[N][K]^T. 4 waves (2x2), wave 64x64, BK=32.
// EPI: C = acc / ((m & 2047)+1) + bias[n].  OBF: C is bf16.
// CS: for n0>=512 also write 64-row column sums to scr[b][seg][col-512].
template <int EPI, int OBF, int CS>
__device__ __forceinline__ void mfma_tile(
    const short* __restrict__ A, const short* __restrict__ B, void* __restrict__ Cv,
    int K, int ldA, int ldB, int ldC, int m0, int n0,
    const float* __restrict__ bias, float* __restrict__ scr, short* L) {
  short* As0 = L;          short* Bs0 = L + 4096;
  short* As1 = L + 8192;   short* Bs1 = L + 12288;
  const int tid = threadIdx.x;
  const int l = tid & 63;
  const int wv = tid >> 6;
  const int wm = (wv >> 1) * 64, wn = (wv & 1) * 64;
  const int sr = tid >> 2, sc = (tid & 3) * 8;
  const short* gA = A + (size_t)(m0 + sr) * ldA + sc;
  const short* gB = B + (size_t)(n0 + sr) * ldB + sc;
  const int so = sr * 32 + sc;
  const int arow = wm + (l & 15), brow = wn + (l & 15);
  const int kc = (l >> 4) * 8;

  f32x4 acc[4][4] = {};

  // prologue: stage tile 0 into buf0
  gload16(gA, As0 + so); gload16(gA + (size_t)64 * ldA, As0 + so + 2048);
  gload16(gB, Bs0 + so); gload16(gB + (size_t)64 * ldB, Bs0 + so + 2048);
  gA += 32; gB += 32;
  asm volatile("s_waitcnt vmcnt(0)" ::: "memory");
  __builtin_amdgcn_s_barrier();
  __builtin_amdgcn_sched_barrier(0);

  const int nt = K >> 5;  // even for all our K (1024, 512)
  for (int t = 0; t < nt; t += 2) {
    // ---- phase 0: stage t+1 -> buf1, compute buf0 ----
    {
      gload16(gA, As1 + so); gload16(gA + (size_t)64 * ldA, As1 + so + 2048);
      gload16(gB, Bs1 + so); gload16(gB + (size_t)64 * ldB, Bs1 + so + 2048);
      gA += 32; gB += 32;
      bf16x8 af[4], bfr[4];
#pragma unroll
      for (int m = 0; m < 4; ++m) af[m] = *(const bf16x8*)&As0[(arow + m * 16) * 32 + kc];
#pragma unroll
      for (int n = 0; n < 4; ++n) bfr[n] = *(const bf16x8*)&Bs0[(brow + n * 16) * 32 + kc];
      asm volatile("s_waitcnt lgkmcnt(0)" ::: "memory");
      __builtin_amdgcn_sched_barrier(0);
#pragma unroll
      for (int m = 0; m < 4; ++m)
#pragma unroll
        for (int n = 0; n < 4; ++n)
          acc[m][n] = __builtin_amdgcn_mfma_f32_16x16x32_bf16(af[m], bfr[n], acc[m][n], 0, 0, 0);
      asm volatile("s_waitcnt vmcnt(0)" ::: "memory");
      __builtin_amdgcn_s_barrier();
      __builtin_amdgcn_sched_barrier(0);
    }
    // ---- phase 1: stage t+2 -> buf0 (if any), compute buf1 ----
    {
      if (t + 2 < nt) {
        gload16(gA, As0 + so); gload16(gA + (size_t)64 * ldA, As0 + so + 2048);
        gload16(gB, Bs0 + so); gload16(gB + (size_t)64 * ldB, Bs0 + so + 2048);
        gA += 32; gB += 32;
      }
      bf16x8 af[4], bfr[4];
#pragma unroll
      for (int m = 0; m < 4; ++m) af[m] = *(const bf16x8*)&As1[(arow + m * 16) * 32 + kc];
#pragma unroll
      for (int n = 0; n < 4; ++n) bfr[n] = *(const bf16x8*)&Bs1[(brow + n * 16) * 32 + kc];
      asm volatile("s_waitcnt lgkmcnt(0)" ::: "memory");
      __builtin_amdgcn_sched_barrier(0);
#pragma unroll
      for (int m = 0; m < 4; ++m)
#pragma unroll
        for (int n = 0; n < 4; ++n)
          acc[m][n] = __builtin_amdgcn_mfma_f32_16x16x32_bf16(af[m], bfr[n], acc[m][n], 0, 0, 0);
      asm volatile("s_waitcnt vmcnt(0)" ::: "memory");
      __builtin_amdgcn_s_barrier();
      __builtin_amdgcn_sched_barrier(0);
    }
  }

  // epilogue. C/D layout: col = l&15, row = (l>>4)*4 + j
  const int cc = wn + (l & 15);
  const int crb = wm + (l >> 4) * 4;
#pragma unroll
  for (int m = 0; m < 4; ++m) {
#pragma unroll
    for (int j = 0; j < 4; ++j) {
      const int gm = m0 + crb + m * 16 + j;
      float inv = 1.0f;
      if (EPI) inv = 1.0f / (float)((gm & (TSEQ - 1)) + 1);
#pragma unroll
      for (int n = 0; n < 4; ++n) {
        const int gn = n0 + cc + n * 16;
        float v = acc[m][n][j];
        if (EPI) v = v * inv + bias[gn];
        if (OBF) ((short*)Cv)[(size_t)gm * ldC + gn] = (short)f2bf(v);
        else     ((float*)Cv)[(size_t)gm * ldC + gn] = v;
      }
    }
  }
  // fused cumsum stage-1: 64-row column sums of this wave's block
  if (CS && n0 >= 512) {
    const int bb = (m0 + wm) >> 11;
    const int seg = ((m0 + wm) & (TSEQ - 1)) >> 6;
    float* sp = scr + (size_t)(bb * 32 + seg) * 768 + (n0 - 512);
#pragma unroll
    for (int n = 0; n < 4; ++n) {
      float s = 0.f;
#pragma unroll
      for (int m = 0; m < 4; ++m)
#pragma unroll
        for (int j = 0; j < 4; ++j) s += acc[m][n][j];
      s += __shfl_xor(s, 16, 64);
      s += __shfl_xor(s, 32, 64);
      if (l < 16) sp[cc + n * 16] = s;
    }
  }
}

template <int EPI, int CS>
__global__ __launch_bounds__(256) void mfma_nt(
    const short* __restrict__ A, const short* __restrict__ B,
    float* __restrict__ C, int K, int ldA, int ldB, int ldC,
    const float* __restrict__ bias, float* __restrict__ scr) {
  __shared__ short L[16384];
  mfma_tile<EPI, 0, CS>(A, B, C, K, ldA, ldB, ldC,
                        blockIdx.y * 128, blockIdx.x * 128, bias, scr, L);
}

// batched prep: 96 blocks = 3 GEMMs x 32 tiles (all K=1024, bf16 out)
__global__ __launch_bounds__(256) void prep_mfma(
    const short* __restrict__ VCT, const short* __restrict__ WQT,
    const short* __restrict__ WCT, const short* __restrict__ WKT,
    const short* __restrict__ WOB, const short* __restrict__ UCT,
    short* __restrict__ Pb, short* __restrict__ Gb) {
  __shared__ short L[16384];
  const int g = blockIdx.x >> 5, t = blockIdx.x & 31;
  if (g == 0)
    mfma_tile<0, 1, 0>(VCT, WQT, Pb, 1024, 1024, 1024, 1024,
                       (t >> 3) * 128, (t & 7) * 128, nullptr, nullptr, L);
  else if (g == 1)
    mfma_tile<0, 1, 0>(WCT, WKT, Pb + (size_t)512 * 1024, 1024, 1024, 1024, 1024,
                       (t >> 3) * 128, (t & 7) * 128, nullptr, nullptr, L);
  else
    mfma_tile<0, 1, 0>(WOB, UCT, Gb, 1024, 1024, 1024, 512,
                       (t >> 2) * 128, (t & 3) * 128, nullptr, nullptr, L);
}

// ============ prep_all: transposes + f2b(Wo) + f2b(x), one launch =============
// bid<960: transpose panels; bid in [960, 10176): f2b over Wo (1M) then x (8M).
__global__ __launch_bounds__(256) void prep_all(
    const float* __restrict__ Vb, const float* __restrict__ Vt,
    const float* __restrict__ Wb, const float* __restrict__ Wt,
    const float* __restrict__ Ub, const float* __restrict__ Ut,
    const float* __restrict__ Xt, const float* __restrict__ Wq,
    const float* __restrict__ Wk, const float* __restrict__ Wo,
    const float* __restrict__ x,
    short* __restrict__ VCT, short* __restrict__ WCT, short* __restrict__ UCT,
    short* __restrict__ PbXt, short* __restrict__ WQT, short* __restrict__ WKT,
    short* __restrict__ WOB, short* __restrict__ xb) {
  const int bid = blockIdx.x;
  const int tid = threadIdx.x;
  if (bid >= 960) {
    const size_t j = ((size_t)(bid - 960) * 256 + tid) * 4;
    const int isWo = j < 1048576u;
    const float* s = isWo ? &Wo[j] : &x[j - 1048576u];
    const float4 v = *(const float4*)s;
    ushort4 o;
    o.x = f2bf(v.x); o.y = f2bf(v.y); o.z = f2bf(v.z); o.w = f2bf(v.w);
    unsigned short* dst = (unsigned short*)(isWo ? WOB : xb);
    *(ushort4*)&dst[isWo ? j : j - 1048576u] = o;
    return;
  }
  const float* src; short* O; int r0, d0, c0, ldS;
  if (bid < 384) {
    const int z = bid >> 7, t = bid & 127;
    r0 = (t >> 4) * 64; d0 = (t & 15) * 64; ldS = 256;
    const float* S0 = z == 0 ? Vb : z == 1 ? Wb : Ub;
    const float* S1 = z == 0 ? Vt : z == 1 ? Wt : Ut;
    O = z == 0 ? VCT : z == 1 ? WCT : UCT;
    src = (r0 < 256) ? S0 : S1; c0 = r0 & 255;
  } else if (bid < 448) {
    const int t = bid - 384;
    r0 = (t >> 4) * 64; d0 = (t & 15) * 64; ldS = 256;
    src = Xt; c0 = r0; O = PbXt;
  } else {
    const int t = bid - 448;
    const int w = t >> 8, tt = t & 255;
    r0 = (tt >> 4) * 64; d0 = (tt & 15) * 64; ldS = 1024;
    src = w ? Wk : Wq; O = w ? WKT : WQT; c0 = r0;
  }
  __shared__ float Ts[64][65];
  const int lr = tid >> 4;
  const int lc = (tid & 15) * 4;
#pragma unroll
  for (int p = 0; p < 4; ++p) {
    const int row = lr + p * 16;
    const float4 v = *(const float4*)&src[(size_t)(d0 + row) * ldS + c0 + lc];
    Ts[row][lc + 0] = v.x; Ts[row][lc + 1] = v.y;
    Ts[row][lc + 2] = v.z; Ts[row][lc + 3] = v.w;
  }
  __syncthreads();
#pragma unroll
  for (int p = 0; p < 4; ++p) {
    const int ri = lr + p * 16;
    ushort4 o;
    o.x = f2bf(Ts[lc + 0][ri]); o.y = f2bf(Ts[lc + 1][ri]);
    o.z = f2bf(Ts[lc + 2][ri]); o.w = f2bf(Ts[lc + 3][ri]);
    *(ushort4*)&((unsigned short*)O)[(size_t)(r0 + ri) * 1024 + d0 + lc] = o;
  }
}

// b2 = Wo @ (bias_b + alpha*bias_t)
__global__ void bias_proj(const float* __restrict__ Wo, const float* __restrict__ bias_b,
                          const float* __restrict__ bias_t, const float* __restrict__ alpha_p,
                          float* __restrict__ b2) {
  const float al = *alpha_p;
  const int d = blockIdx.x;
  const int t = threadIdx.x;
  float s = 0.f;
  for (int e = t; e < 1024; e += 256)
    s += Wo[(size_t)d * 1024 + e] * (bias_b[e] + al * bias_t[e]);
  __shared__ float red[256];
  red[t] = s; __syncthreads();
  for (int off = 128; off > 0; off >>= 1) {
    if (t < off) red[t] += red[t + off];
    __syncthreads();
  }
  if (t == 0) b2[d] = red[0];
}

// scr[b][seg][c] -> exclusive prefix over segs (per batch, per col)
__global__ void cumsum_s2(float* __restrict__ scr) {
  const int lane = threadIdx.x;
  const int cg = blockIdx.x, b = blockIdx.z;
  const int c = cg * 64 + lane;
  float run = 0.f;
  for (int seg = 0; seg < 32; ++seg) {
    const size_t idx = (size_t)(b * 32 + seg) * 768 + c;
    const float v = scr[idx];
    scr[idx] = run;
    run += v;
  }
}

// ============ fused scan stage-3 + combine -> Eb (bf16 [8192][512]) ===========
// block (g, seg, b): cols c2 = g*64+lane in [0,256); walks 64 rows, running
// sums for c_b/c_t/z_t, produces both E halves directly.
__global__ __launch_bounds__(64) void scan_combine(
    const float* __restrict__ Y, const float* __restrict__ scr,
    short* __restrict__ Eb, const float* __restrict__ alpha_p) {
  const float al = *alpha_p;
  const int lane = threadIdx.x;
  const int g = blockIdx.x, seg = blockIdx.y, b = blockIdx.z;
  const int c2 = g * 64 + lane;
  const float* sc = scr + (size_t)(b * 32 + seg) * 768;
  float run_cb = sc[c2];
  float run_ct = sc[256 + c2];
  float run_zt = sc[512 + c2];
  const size_t row0 = (size_t)(b * TSEQ + seg * 64);
  const float* yr = Y + row0 * NCAT;
  float ab = yr[c2], at = yr[256 + c2];
  float cb = yr[512 + c2], ct = yr[768 + c2], zt = yr[1024 + c2];
  for (int tt = 0; tt < 64; ++tt) {
    float nab = 0, nat = 0, ncb = 0, nct = 0, nzt = 0;
    if (tt < 63) {
      const float* yn = yr + NCAT;
      nab = yn[c2]; nat = yn[256 + c2];
      ncb = yn[512 + c2]; nct = yn[768 + c2]; nzt = yn[1024 + c2];
    }
    run_cb += cb; run_ct += ct; run_zt += zt;
    const float inv = 1.0f / (float)(seg * 64 + tt + 1);
    short* er = Eb + (row0 + tt) * 512;
    er[c2]       = (short)f2bf(ab * run_cb);
    er[256 + c2] = (short)f2bf(al * at * (run_zt * inv) * run_ct);
    ab = nab; at = nat; cb = ncb; ct = nct; zt = nzt;
    yr += NCAT;
  }
}

// ================= launch =================
extern "C" void kernel_launch(void* const* d_in, const int* in_sizes, int n_in,
                              void* d_out, int out_size, void* d_ws, size_t ws_size,
                              hipStream_t stream) {
  const float* x      = (const float*)d_in[0];
  const float* Wq     = (const float*)d_in[1];
  const float* Wk     = (const float*)d_in[2];
  const float* Wo     = (const float*)d_in[3];
  const float* Ub     = (const float*)d_in[4];
  const float* Vb     = (const float*)d_in[5];
  const float* Wb     = (const float*)d_in[6];
  const float* bias_b = (const float*)d_in[7];
  const float* Ut     = (const float*)d_in[8];
  const float* Vt     = (const float*)d_in[9];
  const float* Wt     = (const float*)d_in[10];
  const float* Xt     = (const float*)d_in[11];
  const float* bias_t = (const float*)d_in[12];
  const float* alpha  = (const float*)d_in[13];
  float* out = (float*)d_out;
  float* ws  = (float*)d_ws;

  short* WQT = (short*)(ws + OFF_WQT);
  short* WKT = (short*)(ws + OFF_WKT);
  short* WOB = (short*)(ws + OFF_WOB);
  short* VCT = (short*)(ws + OFF_VCT);
  short* WCT = (short*)(ws + OFF_WCT);
  short* UCT = (short*)(ws + OFF_UCT);
  float* b2  = ws + OFF_B2;
  short* Pb  = (short*)(ws + OFF_PB);
  short* Gb  = (short*)(ws + OFF_GB);
  float* Y   = ws + OFF_Y;
  float* scr = ws + OFF_SCR;
  short* xb  = (short*)(ws + OFF_XB);
  short* Eb  = (short*)(ws + OFF_EB);

  // 1. transposes + f2b(Wo) + f2b(x)
  prep_all<<<10176, 256, 0, stream>>>(Vb, Vt, Wb, Wt, Ub, Ut, Xt, Wq, Wk, Wo, x,
                                      VCT, WCT, UCT, Pb + (size_t)1024 * 1024,
                                      WQT, WKT, WOB, xb);
  // 2. batched prep GEMMs (Pb rows 0..1023, Gb), pipelined
  prep_mfma<<<96, 256, 0, stream>>>(VCT, WQT, WCT, WKT, WOB, UCT, Pb, Gb);
  // 3. b2 = Wo @ (bias_b + alpha*bias_t)
  bias_proj<<<1024, 256, 0, stream>>>(Wo, bias_b, bias_t, alpha, b2);
  // 4. Y = xb @ Pb^T (M=8192,N=1280,K=1024) + fused per-seg column sums -> scr
  mfma_nt<0, 1><<<dim3(NCAT / 128, MROWS / 128), 256, 0, stream>>>(
      xb, Pb, Y, 1024, 1024, 1024, NCAT, nullptr, scr);
  // 5. exclusive prefix over segments
  cumsum_s2<<<dim3(12, 1, NBATCH), 64, 0, stream>>>(scr);
  // 6. fused scan+combine -> Eb
  scan_combine<<<dim3(4, 32, NBATCH), 64, 0, stream>>>(Y, scr, Eb, alpha);
  // 7. out = diag(1/counts) * (Eb @ Gb^T) + b2  (M=8192,N=1024,K=512)
  mfma_nt<1, 0><<<dim3(1024 / 128, MROWS / 128), 256, 0, stream>>>(
      Eb, Gb, out, 512, 512, 512, 1024, b2, nullptr);
}

// Round 6
// 221.035 us; speedup vs baseline: 3.1779x; 1.0317x over previous
//
#include <hip/hip_runtime.h>

// Problem constants
#define NBATCH  4
#define TSEQ    2048
#define MROWS   8192
#define NCAT    1280              // 512 (a_b|a_t) + 512 (c_b|c_t) + 256 (z_t)
#define NE      512

// ---- workspace layout (float offsets) ----
#define OFF_WQT   0u                          // Wq^T bf16 [1024][1024]
#define OFF_WKT   524288u                     // Wk^T bf16 [1024][1024]
#define OFF_WOB   1048576u                    // Wo   bf16 [1024][1024]
#define OFF_VCT   1572864u                    // Vc^T bf16 [512][1024]
#define OFF_WCT   1835008u                    // Wc^T bf16 [512][1024]
#define OFF_UCT   2097152u                    // Uc^T bf16 [512][1024]
#define OFF_B2    2359296u                    // [1024] f32
#define OFF_PB    2360320u                    // PcatT bf16 [1280][1024]
#define OFF_GB    3015680u                    // G bf16 [1024][512]
#define OFF_Y     3277824u                    // f32 [8192][1280]
#define OFF_SCR   13763584u                   // f32 [4][32][768]
#define OFF_XB    13861888u                   // x bf16 [8192][1024]
#define OFF_EB    OFF_XB                      // E bf16 [8192][512] (aliases xb)

typedef __attribute__((ext_vector_type(8))) short bf16x8;
typedef __attribute__((ext_vector_type(4))) float f32x4;

__device__ __forceinline__ unsigned short f2bf(float f) {
  union { float f; unsigned u; } v; v.f = f;
  return (unsigned short)((v.u + 0x7fff + ((v.u >> 16) & 1)) >> 16);  // RNE
}

__device__ __forceinline__ void gload16(const void* g, void* l) {
  __builtin_amdgcn_global_load_lds(
      (const __attribute__((address_space(1))) unsigned*)g,
      (__attribute__((address_space(3))) unsigned*)l, 16, 0, 0);
}

// ============ bf16 MFMA NT tile, BK=64, single-buffer, swizzled LDS ===========
// C[m0:+128][n0:+128] = A[M][K]*B[N][K]^T. 4 waves (2x2), wave 64x64.
// LDS tiles [128][64] shorts (stride 128 B). Bank-conflict fix (rule #21):
// global source chunk is pre-swizzled (chunk ^ row&7, stays within the same
// 128 B row -> no extra traffic), LDS write stays linear (gload_lds
// requirement), ds_read XORs the same involution -> 2-way conflict (free).
// EPI: C = acc / ((m & 2047)+1) + bias[n].  OBF: C is bf16.
// CS: for n0>=512 also write 64-row column sums to scr[b][seg][col-512].
template <int EPI, int OBF, int CS>
__device__ __forceinline__ void mfma_tile(
    const short* __restrict__ A, const short* __restrict__ B, void* __restrict__ Cv,
    int K, int ldA, int ldB, int ldC, int m0, int n0,
    const float* __restrict__ bias, float* __restrict__ scr, short* L) {
  short* As = L;            // [128][64]
  short* Bs = L + 8192;     // [128][64]
  const int tid = threadIdx.x;
  const int l = tid & 63;
  const int wv = tid >> 6;
  const int wm = (wv >> 1) * 64, wn = (wv & 1) * 64;
  const int srow = tid >> 3;            // 0..31 (plus p*32)
  const int schk = tid & 7;             // 0..7 (16B chunk in row)
  const int arow = wm + (l & 15), brow = wn + (l & 15);
  const int kq = l >> 4;                // 0..3

  f32x4 acc[4][4] = {};

  for (int k0 = 0; k0 < K; k0 += 64) {
#pragma unroll
    for (int p = 0; p < 4; ++p) {
      const int r = p * 32 + srow;
      const int sw = (schk ^ (r & 7)) * 8;     // swizzled source chunk
      gload16(A + (size_t)(m0 + r) * ldA + k0 + sw, As + r * 64 + schk * 8);
      gload16(B + (size_t)(n0 + r) * ldB + k0 + sw, Bs + r * 64 + schk * 8);
    }
    __syncthreads();
#pragma unroll
    for (int h = 0; h < 2; ++h) {
      bf16x8 af[4], bfr[4];
#pragma unroll
      for (int m = 0; m < 4; ++m) {
        const int r = arow + m * 16;
        af[m] = *(const bf16x8*)&As[r * 64 + (((h * 4 + kq) ^ (r & 7)) * 8)];
      }
#pragma unroll
      for (int n = 0; n < 4; ++n) {
        const int r = brow + n * 16;
        bfr[n] = *(const bf16x8*)&Bs[r * 64 + (((h * 4 + kq) ^ (r & 7)) * 8)];
      }
#pragma unroll
      for (int m = 0; m < 4; ++m)
#pragma unroll
        for (int n = 0; n < 4; ++n)
          acc[m][n] = __builtin_amdgcn_mfma_f32_16x16x32_bf16(af[m], bfr[n], acc[m][n], 0, 0, 0);
    }
    __syncthreads();
  }

  // epilogue. C/D layout: col = l&15, row = (l>>4)*4 + j
  const int cc = wn + (l & 15);
  const int crb = wm + (l >> 4) * 4;
#pragma unroll
  for (int m = 0; m < 4; ++m) {
#pragma unroll
    for (int j = 0; j < 4; ++j) {
      const int gm = m0 + crb + m * 16 + j;
      float inv = 1.0f;
      if (EPI) inv = 1.0f / (float)((gm & (TSEQ - 1)) + 1);
#pragma unroll
      for (int n = 0; n < 4; ++n) {
        const int gn = n0 + cc + n * 16;
        float v = acc[m][n][j];
        if (EPI) v = v * inv + bias[gn];
        if (OBF) ((short*)Cv)[(size_t)gm * ldC + gn] = (short)f2bf(v);
        else     ((float*)Cv)[(size_t)gm * ldC + gn] = v;
      }
    }
  }
  // fused cumsum stage-1: 64-row column sums of this wave's block
  if (CS && n0 >= 512) {
    const int bb = (m0 + wm) >> 11;
    const int seg = ((m0 + wm) & (TSEQ - 1)) >> 6;
    float* sp = scr + (size_t)(bb * 32 + seg) * 768 + (n0 - 512);
#pragma unroll
    for (int n = 0; n < 4; ++n) {
      float s = 0.f;
#pragma unroll
      for (int m = 0; m < 4; ++m)
#pragma unroll
        for (int j = 0; j < 4; ++j) s += acc[m][n][j];
      s += __shfl_xor(s, 16, 64);
      s += __shfl_xor(s, 32, 64);
      if (l < 16) sp[cc + n * 16] = s;
    }
  }
}

template <int EPI, int CS>
__global__ __launch_bounds__(256) void mfma_nt(
    const short* __restrict__ A, const short* __restrict__ B,
    float* __restrict__ C, int K, int ldA, int ldB, int ldC,
    const float* __restrict__ bias, float* __restrict__ scr) {
  __shared__ short L[16384];
  mfma_tile<EPI, 0, CS>(A, B, C, K, ldA, ldB, ldC,
                        blockIdx.y * 128, blockIdx.x * 128, bias, scr, L);
}

// batched prep: 96 blocks = 3 GEMMs x 32 tiles (all K=1024, bf16 out)
__global__ __launch_bounds__(256) void prep_mfma(
    const short* __restrict__ VCT, const short* __restrict__ WQT,
    const short* __restrict__ WCT, const short* __restrict__ WKT,
    const short* __restrict__ WOB, const short* __restrict__ UCT,
    short* __restrict__ Pb, short* __restrict__ Gb) {
  __shared__ short L[16384];
  const int g = blockIdx.x >> 5, t = blockIdx.x & 31;
  if (g == 0)
    mfma_tile<0, 1, 0>(VCT, WQT, Pb, 1024, 1024, 1024, 1024,
                       (t >> 3) * 128, (t & 7) * 128, nullptr, nullptr, L);
  else if (g == 1)
    mfma_tile<0, 1, 0>(WCT, WKT, Pb + (size_t)512 * 1024, 1024, 1024, 1024, 1024,
                       (t >> 3) * 128, (t & 7) * 128, nullptr, nullptr, L);
  else
    mfma_tile<0, 1, 0>(WOB, UCT, Gb, 1024, 1024, 1024, 512,
                       (t >> 2) * 128, (t & 3) * 128, nullptr, nullptr, L);
}

// ===== prep_all: transposes + f2b(Wo) + f2b(x) + bias_proj, one launch ========
// bid<960: transpose panels; [960,10176): f2b Wo then x; >=10176: bias_proj.
__global__ __launch_bounds__(256) void prep_all(
    const float* __restrict__ Vb, const float* __restrict__ Vt,
    const float* __restrict__ Wb, const float* __restrict__ Wt,
    const float* __restrict__ Ub, const float* __restrict__ Ut,
    const float* __restrict__ Xt, const float* __restrict__ Wq,
    const float* __restrict__ Wk, const float* __restrict__ Wo,
    const float* __restrict__ x,
    const float* __restrict__ bias_b, const float* __restrict__ bias_t,
    const float* __restrict__ alpha_p,
    short* __restrict__ VCT, short* __restrict__ WCT, short* __restrict__ UCT,
    short* __restrict__ PbXt, short* __restrict__ WQT, short* __restrict__ WKT,
    short* __restrict__ WOB, short* __restrict__ xb, float* __restrict__ b2) {
  const int bid = blockIdx.x;
  const int tid = threadIdx.x;
  if (bid >= 10176) {                       // bias_proj: d = bid - 10176
    const float al = *alpha_p;
    const int d = bid - 10176;
    float s = 0.f;
    for (int e = tid; e < 1024; e += 256)
      s += Wo[(size_t)d * 1024 + e] * (bias_b[e] + al * bias_t[e]);
    __shared__ float red[256];
    red[tid] = s; __syncthreads();
    for (int off = 128; off > 0; off >>= 1) {
      if (tid < off) red[tid] += red[tid + off];
      __syncthreads();
    }
    if (tid == 0) b2[d] = red[0];
    return;
  }
  if (bid >= 960) {                         // f2b: Wo (1M floats) then x (8M)
    const size_t j = ((size_t)(bid - 960) * 256 + tid) * 4;
    const int isWo = j < 1048576u;
    const float* s = isWo ? &Wo[j] : &x[j - 1048576u];
    const float4 v = *(const float4*)s;
    ushort4 o;
    o.x = f2bf(v.x); o.y = f2bf(v.y); o.z = f2bf(v.z); o.w = f2bf(v.w);
    unsigned short* dst = (unsigned short*)(isWo ? WOB : xb);
    *(ushort4*)&dst[isWo ? j : j - 1048576u] = o;
    return;
  }
  const float* src; short* O; int r0, d0, c0, ldS;
  if (bid < 384) {
    const int z = bid >> 7, t = bid & 127;
    r0 = (t >> 4) * 64; d0 = (t & 15) * 64; ldS = 256;
    const float* S0 = z == 0 ? Vb : z == 1 ? Wb : Ub;
    const float* S1 = z == 0 ? Vt : z == 1 ? Wt : Ut;
    O = z == 0 ? VCT : z == 1 ? WCT : UCT;
    src = (r0 < 256) ? S0 : S1; c0 = r0 & 255;
  } else if (bid < 448) {
    const int t = bid - 384;
    r0 = (t >> 4) * 64; d0 = (t & 15) * 64; ldS = 256;
    src = Xt; c0 = r0; O = PbXt;
  } else {
    const int t = bid - 448;
    const int w = t >> 8, tt = t & 255;
    r0 = (tt >> 4) * 64; d0 = (tt & 15) * 64; ldS = 1024;
    src = w ? Wk : Wq; O = w ? WKT : WQT; c0 = r0;
  }
  __shared__ float Ts[64][65];
  const int lr = tid >> 4;
  const int lc = (tid & 15) * 4;
#pragma unroll
  for (int p = 0; p < 4; ++p) {
    const int row = lr + p * 16;
    const float4 v = *(const float4*)&src[(size_t)(d0 + row) * ldS + c0 + lc];
    Ts[row][lc + 0] = v.x; Ts[row][lc + 1] = v.y;
    Ts[row][lc + 2] = v.z; Ts[row][lc + 3] = v.w;
  }
  __syncthreads();
#pragma unroll
  for (int p = 0; p < 4; ++p) {
    const int ri = lr + p * 16;
    ushort4 o;
    o.x = f2bf(Ts[lc + 0][ri]); o.y = f2bf(Ts[lc + 1][ri]);
    o.z = f2bf(Ts[lc + 2][ri]); o.w = f2bf(Ts[lc + 3][ri]);
    *(ushort4*)&((unsigned short*)O)[(size_t)(r0 + ri) * 1024 + d0 + lc] = o;
  }
}

// scr[b][seg][c] -> exclusive prefix over segs (per batch, per col)
__global__ void cumsum_s2(float* __restrict__ scr) {
  const int lane = threadIdx.x;
  const int cg = blockIdx.x, b = blockIdx.z;
  const int c = cg * 64 + lane;
  float run = 0.f;
  for (int seg = 0; seg < 32; ++seg) {
    const size_t idx = (size_t)(b * 32 + seg) * 768 + c;
    const float v = scr[idx];
    scr[idx] = run;
    run += v;
  }
}

// ============ fused scan stage-3 + combine -> Eb (bf16 [8192][512]) ===========
__global__ __launch_bounds__(64) void scan_combine(
    const float* __restrict__ Y, const float* __restrict__ scr,
    short* __restrict__ Eb, const float* __restrict__ alpha_p) {
  const float al = *alpha_p;
  const int lane = threadIdx.x;
  const int g = blockIdx.x, seg = blockIdx.y, b = blockIdx.z;
  const int c2 = g * 64 + lane;
  const float* sc = scr + (size_t)(b * 32 + seg) * 768;
  float run_cb = sc[c2];
  float run_ct = sc[256 + c2];
  float run_zt = sc[512 + c2];
  const size_t row0 = (size_t)(b * TSEQ + seg * 64);
  const float* yr = Y + row0 * NCAT;
  float ab = yr[c2], at = yr[256 + c2];
  float cb = yr[512 + c2], ct = yr[768 + c2], zt = yr[1024 + c2];
  for (int tt = 0; tt < 64; ++tt) {
    float nab = 0, nat = 0, ncb = 0, nct = 0, nzt = 0;
    if (tt < 63) {
      const float* yn = yr + NCAT;
      nab = yn[c2]; nat = yn[256 + c2];
      ncb = yn[512 + c2]; nct = yn[768 + c2]; nzt = yn[1024 + c2];
    }
    run_cb += cb; run_ct += ct; run_zt += zt;
    const float inv = 1.0f / (float)(seg * 64 + tt + 1);
    short* er = Eb + (row0 + tt) * 512;
    er[c2]       = (short)f2bf(ab * run_cb);
    er[256 + c2] = (short)f2bf(al * at * (run_zt * inv) * run_ct);
    ab = nab; at = nat; cb = ncb; ct = nct; zt = nzt;
    yr += NCAT;
  }
}

// ================= launch =================
extern "C" void kernel_launch(void* const* d_in, const int* in_sizes, int n_in,
                              void* d_out, int out_size, void* d_ws, size_t ws_size,
                              hipStream_t stream) {
  const float* x      = (const float*)d_in[0];
  const float* Wq     = (const float*)d_in[1];
  const float* Wk     = (const float*)d_in[2];
  const float* Wo     = (const float*)d_in[3];
  const float* Ub     = (const float*)d_in[4];
  const float* Vb     = (const float*)d_in[5];
  const float* Wb     = (const float*)d_in[6];
  const float* bias_b = (const float*)d_in[7];
  const float* Ut     = (const float*)d_in[8];
  const float* Vt     = (const float*)d_in[9];
  const float* Wt     = (const float*)d_in[10];
  const float* Xt     = (const float*)d_in[11];
  const float* bias_t = (const float*)d_in[12];
  const float* alpha  = (const float*)d_in[13];
  float* out = (float*)d_out;
  float* ws  = (float*)d_ws;

  short* WQT = (short*)(ws + OFF_WQT);
  short* WKT = (short*)(ws + OFF_WKT);
  short* WOB = (short*)(ws + OFF_WOB);
  short* VCT = (short*)(ws + OFF_VCT);
  short* WCT = (short*)(ws + OFF_WCT);
  short* UCT = (short*)(ws + OFF_UCT);
  float* b2  = ws + OFF_B2;
  short* Pb  = (short*)(ws + OFF_PB);
  short* Gb  = (short*)(ws + OFF_GB);
  float* Y   = ws + OFF_Y;
  float* scr = ws + OFF_SCR;
  short* xb  = (short*)(ws + OFF_XB);
  short* Eb  = (short*)(ws + OFF_EB);

  // 1. transposes + f2b(Wo) + f2b(x) + bias projection
  prep_all<<<11200, 256, 0, stream>>>(Vb, Vt, Wb, Wt, Ub, Ut, Xt, Wq, Wk, Wo, x,
                                      bias_b, bias_t, alpha,
                                      VCT, WCT, UCT, Pb + (size_t)1024 * 1024,
                                      WQT, WKT, WOB, xb, b2);
  // 2. batched prep GEMMs (Pb rows 0..1023, Gb)
  prep_mfma<<<96, 256, 0, stream>>>(VCT, WQT, WCT, WKT, WOB, UCT, Pb, Gb);
  // 3. Y = xb @ Pb^T (M=8192,N=1280,K=1024) + fused per-seg column sums -> scr
  mfma_nt<0, 1><<<dim3(NCAT / 128, MROWS / 128), 256, 0, stream>>>(
      xb, Pb, Y, 1024, 1024, 1024, NCAT, nullptr, scr);
  // 4. exclusive prefix over segments
  cumsum_s2<<<dim3(12, 1, NBATCH), 64, 0, stream>>>(scr);
  // 5. fused scan+combine -> Eb
  scan_combine<<<dim3(4, 32, NBATCH), 64, 0, stream>>>(Y, scr, Eb, alpha);
  // 6. out = diag(1/counts) * (Eb @ Gb^T) + b2  (M=8192,N=1024,K=512)
  mfma_nt<1, 0><<<dim3(1024 / 128, MROWS / 128), 256, 0, stream>>>(
      Eb, Gb, out, 512, 512, 512, 1024, b2, nullptr);
}

// Round 7
// 203.317 us; speedup vs baseline: 3.4548x; 1.0871x over previous
//
#include <hip/hip_runtime.h>

// Problem constants
#define NBATCH  4
#define TSEQ    2048
#define MROWS   8192
#define NCAT    1280              // 512 (a_b|a_t) + 512 (c_b|c_t) + 256 (z_t)
#define NE      512

// ---- workspace layout (float offsets) ----
#define OFF_WQT   0u                          // Wq^T bf16 [1024][1024]
#define OFF_WKT   524288u                     // Wk^T bf16 [1024][1024]
#define OFF_WOB   1048576u                    // Wo   bf16 [1024][1024]
#define OFF_VCT   1572864u                    // Vc^T bf16 [512][1024]
#define OFF_WCT   1835008u                    // Wc^T bf16 [512][1024]
#define OFF_UCT   2097152u                    // Uc^T bf16 [512][1024]
#define OFF_B2    2359296u                    // [1024] f32
#define OFF_PB    2360320u                    // PcatT bf16 [1280][1024]
#define OFF_GB    3015680u                    // G bf16 [1024][512]
#define OFF_Y     3277824u                    // f32 [8192][1280]
#define OFF_SCR   13763584u                   // f32 [4][32][768]
#define OFF_XB    13861888u                   // x bf16 [8192][1024]
#define OFF_EB    OFF_XB                      // E bf16 [8192][512] (aliases xb)

typedef __attribute__((ext_vector_type(8))) short bf16x8;
typedef __attribute__((ext_vector_type(4))) float f32x4;

__device__ __forceinline__ unsigned short f2bf(float f) {
  union { float f; unsigned u; } v; v.f = f;
  return (unsigned short)((v.u + 0x7fff + ((v.u >> 16) & 1)) >> 16);  // RNE
}

__device__ __forceinline__ void gload16(const void* g, void* l) {
  __builtin_amdgcn_global_load_lds(
      (const __attribute__((address_space(1))) unsigned*)g,
      (__attribute__((address_space(3))) unsigned*)l, 16, 0, 0);
}

// ===== bf16 MFMA NT tile, BK=32, LDS double-buffer, COUNTED vmcnt pipeline ====
// C[m0:+128][n0:+128] = A[M][K]*B[N][K]^T. 4 waves (2x2), wave 64x64.
// Per tile each thread issues exactly 4 global_load_lds. Main loop waits
// vmcnt(4): tile-t's loads retired, tile-(t+1)'s 4 stay IN FLIGHT across the
// barrier (T4; never drain to 0 mid-loop). Raw s_barrier ("memory" clobber,
// no sched pins); ds_read->MFMA ordering left to compiler-inserted lgkmcnt.
// Buffer hazard: stage(t+1) writes buf B last read at compute(t-1), sealed by
// the trailing barrier of iteration t-1.
// LDS chunk swizzle (rule #21 both-sides involution): LDS[c] = global[c^(r&3)]
// written via pre-swizzled SOURCE (linear gload_lds dest); read XORs the same.
// EPI: C = acc / ((m & 2047)+1) + bias[n].  OBF: C is bf16.
// CS: for n0>=512 also write 64-row column sums to scr[b][seg][col-512].
template <int EPI, int OBF, int CS>
__device__ __forceinline__ void mfma_tile(
    const short* __restrict__ A, const short* __restrict__ B, void* __restrict__ Cv,
    int K, int ldA, int ldB, int ldC, int m0, int n0,
    const float* __restrict__ bias, float* __restrict__ scr, short* L) {
  const int tid = threadIdx.x;
  const int l = tid & 63;
  const int wv = tid >> 6;
  const int wm = (wv >> 1) * 64, wn = (wv & 1) * 64;
  const int sr = tid >> 2;              // staging row 0..63 (plus p*64)
  const int sc4 = tid & 3;              // 16B chunk 0..3 within 64B row
  const int arow = wm + (l & 15), brow = wn + (l & 15);
  const int kq = l >> 4;                // k-chunk 0..3

  f32x4 acc[4][4] = {};

#define STAGE(k0, par) do {                                                  \
    short* As_ = L + (par) * 8192;                                           \
    short* Bs_ = As_ + 4096;                                                 \
    _Pragma("unroll")                                                        \
    for (int p = 0; p < 2; ++p) {                                            \
      const int r = p * 64 + sr;                                             \
      const int sw = (sc4 ^ (r & 3)) * 8;                                    \
      gload16(A + (size_t)(m0 + r) * ldA + (k0) + sw, As_ + r * 32 + sc4 * 8); \
      gload16(B + (size_t)(n0 + r) * ldB + (k0) + sw, Bs_ + r * 32 + sc4 * 8); \
    }                                                                        \
  } while (0)

#define COMPUTE(par) do {                                                    \
    short* As_ = L + (par) * 8192;                                           \
    short* Bs_ = As_ + 4096;                                                 \
    bf16x8 af[4], bfr[4];                                                    \
    _Pragma("unroll")                                                        \
    for (int m = 0; m < 4; ++m) {                                            \
      const int r = arow + m * 16;                                           \
      af[m] = *(const bf16x8*)&As_[r * 32 + ((kq ^ (r & 3)) * 8)];           \
    }                                                                        \
    _Pragma("unroll")                                                        \
    for (int n = 0; n < 4; ++n) {                                            \
      const int r = brow + n * 16;                                           \
      bfr[n] = *(const bf16x8*)&Bs_[r * 32 + ((kq ^ (r & 3)) * 8)];          \
    }                                                                        \
    _Pragma("unroll")                                                        \
    for (int m = 0; m < 4; ++m)                                              \
      _Pragma("unroll")                                                      \
      for (int n = 0; n < 4; ++n)                                            \
        acc[m][n] = __builtin_amdgcn_mfma_f32_16x16x32_bf16(af[m], bfr[n], acc[m][n], 0, 0, 0); \
  } while (0)

  STAGE(0, 0);
  const int nt = K >> 5;
  for (int t = 0; t < nt; ++t) {
    if (t + 1 < nt) {
      STAGE((t + 1) << 5, (t + 1) & 1);
      asm volatile("s_waitcnt vmcnt(4)" ::: "memory");   // tile-t ready; prefetch in flight
    } else {
      asm volatile("s_waitcnt vmcnt(0)" ::: "memory");   // last tile: drain
    }
    asm volatile("s_barrier" ::: "memory");
    COMPUTE(t & 1);
    asm volatile("s_barrier" ::: "memory");
  }
#undef STAGE
#undef COMPUTE

  // epilogue. C/D layout: col = l&15, row = (l>>4)*4 + j
  const int cc = wn + (l & 15);
  const int crb = wm + (l >> 4) * 4;
#pragma unroll
  for (int m = 0; m < 4; ++m) {
#pragma unroll
    for (int j = 0; j < 4; ++j) {
      const int gm = m0 + crb + m * 16 + j;
      float inv = 1.0f;
      if (EPI) inv = 1.0f / (float)((gm & (TSEQ - 1)) + 1);
#pragma unroll
      for (int n = 0; n < 4; ++n) {
        const int gn = n0 + cc + n * 16;
        float v = acc[m][n][j];
        if (EPI) v = v * inv + bias[gn];
        if (OBF) ((short*)Cv)[(size_t)gm * ldC + gn] = (short)f2bf(v);
        else     ((float*)Cv)[(size_t)gm * ldC + gn] = v;
      }
    }
  }
  // fused cumsum stage-1: 64-row column sums of this wave's block
  if (CS && n0 >= 512) {
    const int bb = (m0 + wm) >> 11;
    const int seg = ((m0 + wm) & (TSEQ - 1)) >> 6;
    float* sp = scr + (size_t)(bb * 32 + seg) * 768 + (n0 - 512);
#pragma unroll
    for (int n = 0; n < 4; ++n) {
      float s = 0.f;
#pragma unroll
      for (int m = 0; m < 4; ++m)
#pragma unroll
        for (int j = 0; j < 4; ++j) s += acc[m][n][j];
      s += __shfl_xor(s, 16, 64);
      s += __shfl_xor(s, 32, 64);
      if (l < 16) sp[cc + n * 16] = s;
    }
  }
}

// XCD-aware bijective swizzle of the linearized block id (nwg % 8 == 0).
__device__ __forceinline__ void xcd_swizzle(int& bx, int& by) {
  const int gx = gridDim.x;
  const int nwg = gx * gridDim.y;
  const int n = by * gx + bx;
  const int q = nwg >> 3;
  const int s = (n & 7) * q + (n >> 3);
  bx = s % gx; by = s / gx;
}

template <int EPI, int CS>
__global__ __launch_bounds__(256) void mfma_nt(
    const short* __restrict__ A, const short* __restrict__ B,
    float* __restrict__ C, int K, int ldA, int ldB, int ldC,
    const float* __restrict__ bias, float* __restrict__ scr) {
  __shared__ short L[16384];
  int bx = blockIdx.x, by = blockIdx.y;
  xcd_swizzle(bx, by);
  mfma_tile<EPI, 0, CS>(A, B, C, K, ldA, ldB, ldC,
                        by * 128, bx * 128, bias, scr, L);
}

// batched prep: 96 blocks = 3 GEMMs x 32 tiles (all K=1024, bf16 out)
__global__ __launch_bounds__(256) void prep_mfma(
    const short* __restrict__ VCT, const short* __restrict__ WQT,
    const short* __restrict__ WCT, const short* __restrict__ WKT,
    const short* __restrict__ WOB, const short* __restrict__ UCT,
    short* __restrict__ Pb, short* __restrict__ Gb) {
  __shared__ short L[16384];
  const int g = blockIdx.x >> 5, t = blockIdx.x & 31;
  if (g == 0)
    mfma_tile<0, 1, 0>(VCT, WQT, Pb, 1024, 1024, 1024, 1024,
                       (t >> 3) * 128, (t & 7) * 128, nullptr, nullptr, L);
  else if (g == 1)
    mfma_tile<0, 1, 0>(WCT, WKT, Pb + (size_t)512 * 1024, 1024, 1024, 1024, 1024,
                       (t >> 3) * 128, (t & 7) * 128, nullptr, nullptr, L);
  else
    mfma_tile<0, 1, 0>(WOB, UCT, Gb, 1024, 1024, 1024, 512,
                       (t >> 2) * 128, (t & 3) * 128, nullptr, nullptr, L);
}

// ===== prep_all: transposes + f2b(Wo) + f2b(x) + bias_proj, one launch ========
__global__ __launch_bounds__(256) void prep_all(
    const float* __restrict__ Vb, const float* __restrict__ Vt,
    const float* __restrict__ Wb, const float* __restrict__ Wt,
    const float* __restrict__ Ub, const float* __restrict__ Ut,
    const float* __restrict__ Xt, const float* __restrict__ Wq,
    const float* __restrict__ Wk, const float* __restrict__ Wo,
    const float* __restrict__ x,
    const float* __restrict__ bias_b, const float* __restrict__ bias_t,
    const float* __restrict__ alpha_p,
    short* __restrict__ VCT, short* __restrict__ WCT, short* __restrict__ UCT,
    short* __restrict__ PbXt, short* __restrict__ WQT, short* __restrict__ WKT,
    short* __restrict__ WOB, short* __restrict__ xb, float* __restrict__ b2) {
  const int bid = blockIdx.x;
  const int tid = threadIdx.x;
  if (bid >= 10176) {                       // bias_proj: d = bid - 10176
    const float al = *alpha_p;
    const int d = bid - 10176;
    float s = 0.f;
    for (int e = tid; e < 1024; e += 256)
      s += Wo[(size_t)d * 1024 + e] * (bias_b[e] + al * bias_t[e]);
    __shared__ float red[256];
    red[tid] = s; __syncthreads();
    for (int off = 128; off > 0; off >>= 1) {
      if (tid < off) red[tid] += red[tid + off];
      __syncthreads();
    }
    if (tid == 0) b2[d] = red[0];
    return;
  }
  if (bid >= 960) {                         // f2b: Wo (1M floats) then x (8M)
    const size_t j = ((size_t)(bid - 960) * 256 + tid) * 4;
    const int isWo = j < 1048576u;
    const float* s = isWo ? &Wo[j] : &x[j - 1048576u];
    const float4 v = *(const float4*)s;
    ushort4 o;
    o.x = f2bf(v.x); o.y = f2bf(v.y); o.z = f2bf(v.z); o.w = f2bf(v.w);
    unsigned short* dst = (unsigned short*)(isWo ? WOB : xb);
    *(ushort4*)&dst[isWo ? j : j - 1048576u] = o;
    return;
  }
  const float* src; short* O; int r0, d0, c0, ldS;
  if (bid < 384) {
    const int z = bid >> 7, t = bid & 127;
    r0 = (t >> 4) * 64; d0 = (t & 15) * 64; ldS = 256;
    const float* S0 = z == 0 ? Vb : z == 1 ? Wb : Ub;
    const float* S1 = z == 0 ? Vt : z == 1 ? Wt : Ut;
    O = z == 0 ? VCT : z == 1 ? WCT : UCT;
    src = (r0 < 256) ? S0 : S1; c0 = r0 & 255;
  } else if (bid < 448) {
    const int t = bid - 384;
    r0 = (t >> 4) * 64; d0 = (t & 15) * 64; ldS = 256;
    src = Xt; c0 = r0; O = PbXt;
  } else {
    const int t = bid - 448;
    const int w = t >> 8, tt = t & 255;
    r0 = (tt >> 4) * 64; d0 = (tt & 15) * 64; ldS = 1024;
    src = w ? Wk : Wq; O = w ? WKT : WQT; c0 = r0;
  }
  __shared__ float Ts[64][65];
  const int lr = tid >> 4;
  const int lc = (tid & 15) * 4;
#pragma unroll
  for (int p = 0; p < 4; ++p) {
    const int row = lr + p * 16;
    const float4 v = *(const float4*)&src[(size_t)(d0 + row) * ldS + c0 + lc];
    Ts[row][lc + 0] = v.x; Ts[row][lc + 1] = v.y;
    Ts[row][lc + 2] = v.z; Ts[row][lc + 3] = v.w;
  }
  __syncthreads();
#pragma unroll
  for (int p = 0; p < 4; ++p) {
    const int ri = lr + p * 16;
    ushort4 o;
    o.x = f2bf(Ts[lc + 0][ri]); o.y = f2bf(Ts[lc + 1][ri]);
    o.z = f2bf(Ts[lc + 2][ri]); o.w = f2bf(Ts[lc + 3][ri]);
    *(ushort4*)&((unsigned short*)O)[(size_t)(r0 + ri) * 1024 + d0 + lc] = o;
  }
}

// scr[b][seg][c] -> exclusive prefix over segs (per batch, per col)
__global__ void cumsum_s2(float* __restrict__ scr) {
  const int lane = threadIdx.x;
  const int cg = blockIdx.x, b = blockIdx.z;
  const int c = cg * 64 + lane;
  float run = 0.f;
  for (int seg = 0; seg < 32; ++seg) {
    const size_t idx = (size_t)(b * 32 + seg) * 768 + c;
    const float v = scr[idx];
    scr[idx] = run;
    run += v;
  }
}

// ===== fused scan stage-3 + combine -> Eb (bf16 [8192][512]), 256 thr/block ===
// block (seg, b): thread = c2 in [0,256); 5 coalesced 1KB row-segments/row.
__global__ __launch_bounds__(256) void scan_combine(
    const float* __restrict__ Y, const float* __restrict__ scr,
    short* __restrict__ Eb, const float* __restrict__ alpha_p) {
  const float al = *alpha_p;
  const int c2 = threadIdx.x;
  const int seg = blockIdx.x, b = blockIdx.y;
  const float* sc = scr + (size_t)(b * 32 + seg) * 768;
  float run_cb = sc[c2];
  float run_ct = sc[256 + c2];
  float run_zt = sc[512 + c2];
  const size_t row0 = (size_t)(b * TSEQ + seg * 64);
  const float* yr = Y + row0 * NCAT;
  float ab = yr[c2], at = yr[256 + c2];
  float cb = yr[512 + c2], ct = yr[768 + c2], zt = yr[1024 + c2];
  for (int tt = 0; tt < 64; ++tt) {
    float nab = 0, nat = 0, ncb = 0, nct = 0, nzt = 0;
    if (tt < 63) {
      const float* yn = yr + NCAT;
      nab = yn[c2]; nat = yn[256 + c2];
      ncb = yn[512 + c2]; nct = yn[768 + c2]; nzt = yn[1024 + c2];
    }
    run_cb += cb; run_ct += ct; run_zt += zt;
    const float inv = 1.0f / (float)(seg * 64 + tt + 1);
    short* er = Eb + (row0 + tt) * 512;
    er[c2]       = (short)f2bf(ab * run_cb);
    er[256 + c2] = (short)f2bf(al * at * (run_zt * inv) * run_ct);
    ab = nab; at = nat; cb = ncb; ct = nct; zt = nzt;
    yr += NCAT;
  }
}

// ================= launch =================
extern "C" void kernel_launch(void* const* d_in, const int* in_sizes, int n_in,
                              void* d_out, int out_size, void* d_ws, size_t ws_size,
                              hipStream_t stream) {
  const float* x      = (const float*)d_in[0];
  const float* Wq     = (const float*)d_in[1];
  const float* Wk     = (const float*)d_in[2];
  const float* Wo     = (const float*)d_in[3];
  const float* Ub     = (const float*)d_in[4];
  const float* Vb     = (const float*)d_in[5];
  const float* Wb     = (const float*)d_in[6];
  const float* bias_b = (const float*)d_in[7];
  const float* Ut     = (const float*)d_in[8];
  const float* Vt     = (const float*)d_in[9];
  const float* Wt     = (const float*)d_in[10];
  const float* Xt     = (const float*)d_in[11];
  const float* bias_t = (const float*)d_in[12];
  const float* alpha  = (const float*)d_in[13];
  float* out = (float*)d_out;
  float* ws  = (float*)d_ws;

  short* WQT = (short*)(ws + OFF_WQT);
  short* WKT = (short*)(ws + OFF_WKT);
  short* WOB = (short*)(ws + OFF_WOB);
  short* VCT = (short*)(ws + OFF_VCT);
  short* WCT = (short*)(ws + OFF_WCT);
  short* UCT = (short*)(ws + OFF_UCT);
  float* b2  = ws + OFF_B2;
  short* Pb  = (short*)(ws + OFF_PB);
  short* Gb  = (short*)(ws + OFF_GB);
  float* Y   = ws + OFF_Y;
  float* scr = ws + OFF_SCR;
  short* xb  = (short*)(ws + OFF_XB);
  short* Eb  = (short*)(ws + OFF_EB);

  // 1. transposes + f2b(Wo) + f2b(x) + bias projection
  prep_all<<<11200, 256, 0, stream>>>(Vb, Vt, Wb, Wt, Ub, Ut, Xt, Wq, Wk, Wo, x,
                                      bias_b, bias_t, alpha,
                                      VCT, WCT, UCT, Pb + (size_t)1024 * 1024,
                                      WQT, WKT, WOB, xb, b2);
  // 2. batched prep GEMMs (Pb rows 0..1023, Gb)
  prep_mfma<<<96, 256, 0, stream>>>(VCT, WQT, WCT, WKT, WOB, UCT, Pb, Gb);
  // 3. Y = xb @ Pb^T (M=8192,N=1280,K=1024) + fused per-seg column sums -> scr
  mfma_nt<0, 1><<<dim3(NCAT / 128, MROWS / 128), 256, 0, stream>>>(
      xb, Pb, Y, 1024, 1024, 1024, NCAT, nullptr, scr);
  // 4. exclusive prefix over segments
  cumsum_s2<<<dim3(12, 1, NBATCH), 64, 0, stream>>>(scr);
  // 5. fused scan+combine -> Eb
  scan_combine<<<dim3(32, NBATCH), 256, 0, stream>>>(Y, scr, Eb, alpha);
  // 6. out = diag(1/counts) * (Eb @ Gb^T) + b2  (M=8192,N=1024,K=512)
  mfma_nt<1, 0><<<dim3(1024 / 128, MROWS / 128), 256, 0, stream>>>(
      Eb, Gb, out, 512, 512, 512, 1024, b2, nullptr);
}